// Round 2
// baseline (23223.866 us; speedup 1.0000x reference)
//
#include <hip/hip_runtime.h>
#include <hip/hip_bf16.h>

typedef __hip_bfloat16 bf16;

#define BB 4
#define HH 128
#define WWI 128
#define NN 16384      // HH*WWI
#define CC 256
#define LL 4
#define NHEADS 8
#define DHD 32
#define GG 64
#define INNERC 256    // NHEADS*DHD
#define HIDD 1024

__device__ __forceinline__ float b2f(bf16 x) { return __bfloat162float(x); }
__device__ __forceinline__ bf16 f2b(float x) { return __float2bfloat16(x); }

__device__ __forceinline__ float wave_sum(float v) {
#pragma unroll
  for (int off = 32; off > 0; off >>= 1) v += __shfl_down(v, off, 64);
  return v;
}

__device__ __forceinline__ float gelu_exact(float x) {
  return 0.5f * x * (1.0f + erff(x * 0.70710678118654752f));
}

// ---------- LayerNorm over C=256 per point; block = 256 threads ----------
__global__ void ln_kernel(const float* __restrict__ x, const float* __restrict__ w,
                          const float* __restrict__ b, bf16* __restrict__ out) {
  int pp = blockIdx.x;
  int t = threadIdx.x;
  float v = x[(size_t)pp * CC + t];
  float s = wave_sum(v);
  float sq = wave_sum(v * v);
  __shared__ float ls[4], lq[4];
  int wid = t >> 6, lane = t & 63;
  if (lane == 0) { ls[wid] = s; lq[wid] = sq; }
  __syncthreads();
  float tot = ls[0] + ls[1] + ls[2] + ls[3];
  float totq = lq[0] + lq[1] + lq[2] + lq[3];
  float mean = tot * (1.0f / CC);
  float var = totq * (1.0f / CC) - mean * mean;
  float rstd = rsqrtf(var + 1e-5f);
  float o = (v - mean) * rstd * w[t] + b[t];
  out[(size_t)pp * CC + t] = f2b(o);
}

// ---------- 3x3 SAME conv, NHWC, weights [3,3,C,INNER]; 16-pixel strip/block ----------
__global__ __launch_bounds__(256) void conv3x3_kernel(
    const bf16* __restrict__ xln, const float* __restrict__ w,
    const float* __restrict__ bias, bf16* __restrict__ out) {
  __shared__ float xs[3][CC][20];  // rows hh-1..hh+1, cols ww0-1..ww0+16 (18 used, pad 20)
  int bid = blockIdx.x;            // B * H * (W/16)
  const int wb = WWI / 16;         // 8
  int b = bid / (HH * wb);
  int rem = bid % (HH * wb);
  int hh = rem / wb;
  int ww0 = (rem % wb) * 16;
  int t = threadIdx.x;             // 256

  for (int idx = t; idx < 3 * 18 * CC; idx += 256) {
    int c = idx & 255;
    int rc = idx >> 8;             // 0..53
    int row = rc / 18, col = rc % 18;
    int gr = hh + row - 1, gc = ww0 + col - 1;
    float v = 0.0f;
    if (gr >= 0 && gr < HH && gc >= 0 && gc < WWI)
      v = b2f(xln[((size_t)(b * NN + gr * WWI + gc)) * CC + c]);
    xs[row][c][col] = v;
  }
  __syncthreads();

  int o = t;                       // output channel
  float acc[16];
  float bv = bias[o];
#pragma unroll
  for (int p = 0; p < 16; ++p) acc[p] = bv;
  for (int ky = 0; ky < 3; ++ky) {
    const float* w0p = w + ((size_t)(ky * 3 + 0) * CC) * INNERC + o;
    const float* w1p = w + ((size_t)(ky * 3 + 1) * CC) * INNERC + o;
    const float* w2p = w + ((size_t)(ky * 3 + 2) * CC) * INNERC + o;
#pragma unroll 2
    for (int c = 0; c < CC; ++c) {
      float w0 = w0p[(size_t)c * INNERC];
      float w1v = w1p[(size_t)c * INNERC];
      float w2v = w2p[(size_t)c * INNERC];
      const float* xr = xs[ky][c];
#pragma unroll
      for (int p = 0; p < 16; ++p)
        acc[p] += xr[p] * w0 + xr[p + 1] * w1v + xr[p + 2] * w2v;
    }
  }
  size_t pbase = ((size_t)(b * NN + hh * WWI + ww0)) * INNERC + o;
#pragma unroll
  for (int p = 0; p < 16; ++p) out[pbase + (size_t)p * INNERC] = f2b(acc[p]);
}

// ---------- slice logits + softmax over G; block = 512 = 8 heads x 64 g ----------
__global__ void slice_softmax_kernel(const bf16* __restrict__ xmid, const float* __restrict__ sw_w,
                                     const float* __restrict__ sw_b, const float* __restrict__ temp,
                                     bf16* __restrict__ swout) {
  __shared__ float xm[CC];
  int pp = blockIdx.x;
  int t = threadIdx.x;   // 512
  if (t < CC) xm[t] = b2f(xmid[(size_t)pp * CC + t]);
  __syncthreads();
  int h = t >> 6, g = t & 63;
  float acc = sw_b[g];
  const float* xp = &xm[h * DHD];
#pragma unroll
  for (int d = 0; d < DHD; ++d)
    acc += xp[d] * sw_w[d * GG + g];
  float tc = temp[h];
  tc = fminf(fmaxf(tc, 0.1f), 5.0f);
  float logit = acc / tc;
  float m = logit;
#pragma unroll
  for (int off = 32; off > 0; off >>= 1) m = fmaxf(m, __shfl_xor(m, off, 64));
  float e = __expf(logit - m);
  float s = e;
#pragma unroll
  for (int off = 32; off > 0; off >>= 1) s += __shfl_xor(s, off, 64);
  swout[(size_t)pp * (NHEADS * GG) + t] = f2b(e / s);
}

// ---------- st_raw[b,h,g,:] = sum_n fxmid*sw ; norm[b,h,g] = sum_n sw ----------
__global__ void slice_reduce_kernel(const bf16* __restrict__ fxmid, const bf16* __restrict__ sw,
                                    float* __restrict__ st_raw, float* __restrict__ normbuf) {
  int blk = blockIdx.x;   // B*8*64
  int g = blk & 63;
  int h = (blk >> 6) & 7;
  int b = blk >> 9;
  int t = threadIdx.x;    // 256
  int sub = t >> 5, d = t & 31;
  float acc = 0.0f, nacc = 0.0f;
  const bf16* swp = sw + ((size_t)b * NN) * (NHEADS * GG) + h * GG + g;
  const bf16* fxp = fxmid + ((size_t)b * NN) * INNERC + h * DHD + d;
  for (int n = sub; n < NN; n += 8) {
    float s = b2f(swp[(size_t)n * (NHEADS * GG)]);
    float f = b2f(fxp[(size_t)n * INNERC]);
    acc += f * s;
    nacc += s;
  }
  __shared__ float red[8][32];
  __shared__ float nred[8];
  red[sub][d] = acc;
  if (d == 0) nred[sub] = nacc;
  __syncthreads();
  if (sub == 0) {
    float tot = 0.0f;
#pragma unroll
    for (int s2 = 0; s2 < 8; ++s2) tot += red[s2][d];
    st_raw[(size_t)blk * DHD + d] = tot;
    if (d == 0) {
      float nt = 0.0f;
#pragma unroll
      for (int s2 = 0; s2 < 8; ++s2) nt += nred[s2];
      normbuf[blk] = nt;
    }
  }
}

// ---------- tiny attention over G=64 tokens, per (b,h); block = 64 threads ----------
__global__ void attn_kernel(const float* __restrict__ st_raw, const float* __restrict__ normbuf,
                            const float* __restrict__ wq, const float* __restrict__ wk,
                            const float* __restrict__ wv, float* __restrict__ ot) {
  int bh = blockIdx.x;     // B*8
  int g = threadIdx.x;     // 64
  __shared__ float st[GG][DHD], kk[GG][DHD], vv[GG][DHD];
  float rn = 1.0f / (normbuf[bh * GG + g] + 1e-5f);
#pragma unroll
  for (int d = 0; d < DHD; ++d)
    st[g][d] = st_raw[((size_t)bh * GG + g) * DHD + d] * rn;
  __syncthreads();
  float q[DHD];
#pragma unroll
  for (int d = 0; d < DHD; ++d) {
    float aq = 0, ak = 0, av = 0;
#pragma unroll
    for (int c = 0; c < DHD; ++c) {
      float sv = st[g][c];
      aq += sv * wq[c * DHD + d];
      ak += sv * wk[c * DHD + d];
      av += sv * wv[c * DHD + d];
    }
    q[d] = aq; kk[g][d] = ak; vv[g][d] = av;
  }
  __syncthreads();
  float sc[GG];
  float m = -1e30f;
  const float scale = 0.17677669529663687f;   // 1/sqrt(32)
#pragma unroll
  for (int j = 0; j < GG; ++j) {
    float a = 0;
#pragma unroll
    for (int d = 0; d < DHD; ++d) a += q[d] * kk[j][d];
    a *= scale;
    sc[j] = a;
    m = fmaxf(m, a);
  }
  float s = 0;
#pragma unroll
  for (int j = 0; j < GG; ++j) { sc[j] = __expf(sc[j] - m); s += sc[j]; }
  float rs = 1.0f / s;
#pragma unroll
  for (int d = 0; d < DHD; ++d) {
    float a = 0;
#pragma unroll
    for (int j = 0; j < GG; ++j) a += sc[j] * vv[j][d];
    ot[((size_t)bh * GG + g) * DHD + d] = a * rs;
  }
}

// ---------- deslice (ot·sw) fused with out_x@wo + bo; 4 points/block ----------
__global__ __launch_bounds__(256) void deslice_proj_kernel(
    const float* __restrict__ ot, const bf16* __restrict__ sw,
    const float* __restrict__ wo, const float* __restrict__ bo,
    float* __restrict__ fx) {
  __shared__ float swl[NHEADS * GG][4];   // 8 KiB
  __shared__ float outx[INNERC][4];       // 4 KiB
  int p0 = blockIdx.x * 4;                // point base (b*N + n)
  int b = blockIdx.x / (NN / 4);
  int t = threadIdx.x;                    // 256
  for (int idx = t; idx < 4 * 512; idx += 256) {
    int p = idx >> 9, g2 = idx & 511;
    swl[g2][p] = b2f(sw[(size_t)(p0 + p) * (NHEADS * GG) + g2]);
  }
  __syncthreads();
  int h = t >> 5, d = t & 31;
  float acc[4] = {0.f, 0.f, 0.f, 0.f};
  const float* otp = ot + ((size_t)(b * NHEADS + h) * GG) * DHD + d;
#pragma unroll 4
  for (int g = 0; g < GG; ++g) {
    float ov = otp[(size_t)g * DHD];
    const float* sv = swl[h * GG + g];
#pragma unroll
    for (int p = 0; p < 4; ++p) acc[p] += ov * sv[p];
  }
#pragma unroll
  for (int p = 0; p < 4; ++p) outx[t][p] = acc[p];
  __syncthreads();
  float a2[4];
  float bv = bo[t];
#pragma unroll
  for (int p = 0; p < 4; ++p) a2[p] = bv;
  const float* wop = wo + t;
  for (int k = 0; k < INNERC; ++k) {
    float wv = wop[(size_t)k * CC];
    const float* xr = outx[k];
#pragma unroll
    for (int p = 0; p < 4; ++p) a2[p] += xr[p] * wv;
  }
#pragma unroll
  for (int p = 0; p < 4; ++p) fx[(size_t)(p0 + p) * CC + t] += a2[p];
}

// ---------- fused MLP: fx += gelu(xln@w1+b1)@w2+b2 ; 8 points/block ----------
__global__ __launch_bounds__(256) void mlp_kernel(
    const bf16* __restrict__ xln, const float* __restrict__ w1,
    const float* __restrict__ b1, const float* __restrict__ w2,
    const float* __restrict__ b2, float* __restrict__ fx) {
  __shared__ float xin[CC][8];    // 8 KiB
  __shared__ float hid[HIDD][8];  // 32 KiB
  int p0 = blockIdx.x * 8;
  int t = threadIdx.x;            // 256
  for (int idx = t; idx < 8 * CC; idx += 256) {
    int p = idx >> 8, c = idx & 255;
    xin[c][p] = b2f(xln[(size_t)(p0 + p) * CC + c]);
  }
  __syncthreads();
  for (int j = t; j < HIDD; j += 256) {
    float a[8];
    float bb = b1[j];
#pragma unroll
    for (int p = 0; p < 8; ++p) a[p] = bb;
    const float* wp = w1 + j;
#pragma unroll 2
    for (int c = 0; c < CC; ++c) {
      float wv = wp[(size_t)c * HIDD];
      const float* xr = xin[c];
#pragma unroll
      for (int p = 0; p < 8; ++p) a[p] += xr[p] * wv;
    }
#pragma unroll
    for (int p = 0; p < 8; ++p) hid[j][p] = gelu_exact(a[p]);
  }
  __syncthreads();
  float acc[8];
  float bb = b2[t];
#pragma unroll
  for (int p = 0; p < 8; ++p) acc[p] = bb;
  const float* wp2 = w2 + t;
#pragma unroll 2
  for (int j = 0; j < HIDD; ++j) {
    float wv = wp2[(size_t)j * CC];
    const float* hr = hid[j];
#pragma unroll
    for (int p = 0; p < 8; ++p) acc[p] += hr[p] * wv;
  }
#pragma unroll
  for (int p = 0; p < 8; ++p) fx[(size_t)(p0 + p) * CC + t] += acc[p];
}

// ---------- final LN3 + head (C -> 4) ----------
__global__ void head_kernel(const float* __restrict__ fx, const float* __restrict__ w,
                            const float* __restrict__ b, const float* __restrict__ wout,
                            const float* __restrict__ bout, float* __restrict__ out) {
  int pp = blockIdx.x;
  int t = threadIdx.x;
  float v = fx[(size_t)pp * CC + t];
  float s = wave_sum(v);
  float sq = wave_sum(v * v);
  __shared__ float ls[4], lq[4];
  int wid = t >> 6, lane = t & 63;
  if (lane == 0) { ls[wid] = s; lq[wid] = sq; }
  __syncthreads();
  float tot = ls[0] + ls[1] + ls[2] + ls[3];
  float totq = lq[0] + lq[1] + lq[2] + lq[3];
  float mean = tot * (1.0f / CC);
  float var = totq * (1.0f / CC) - mean * mean;
  float rstd = rsqrtf(var + 1e-5f);
  float xn = (v - mean) * rstd * w[t] + b[t];
  __shared__ float xs[CC];
  xs[t] = xn;
  __syncthreads();
  if (t < 4) {
    float a = bout[t];
    for (int c = 0; c < CC; ++c) a += xs[c] * wout[c * 4 + t];
    out[(size_t)pp * 4 + t] = a;
  }
}

extern "C" void kernel_launch(void* const* d_in, const int* in_sizes, int n_in,
                              void* d_out, int out_size, void* d_ws, size_t ws_size,
                              hipStream_t stream) {
  const float* fx_in      = (const float*)d_in[0];
  const float* ln1_w      = (const float*)d_in[1];
  const float* ln1_b      = (const float*)d_in[2];
  const float* convx_w    = (const float*)d_in[3];
  const float* convx_b    = (const float*)d_in[4];
  const float* convfx_w   = (const float*)d_in[5];
  const float* convfx_b   = (const float*)d_in[6];
  const float* slice_w    = (const float*)d_in[7];
  const float* slice_b    = (const float*)d_in[8];
  const float* temperature= (const float*)d_in[9];
  const float* wq         = (const float*)d_in[10];
  const float* wk         = (const float*)d_in[11];
  const float* wv         = (const float*)d_in[12];
  const float* wo         = (const float*)d_in[13];
  const float* bo         = (const float*)d_in[14];
  const float* ln2_w      = (const float*)d_in[15];
  const float* ln2_b      = (const float*)d_in[16];
  const float* w1         = (const float*)d_in[17];
  const float* b1         = (const float*)d_in[18];
  const float* w2         = (const float*)d_in[19];
  const float* b2         = (const float*)d_in[20];
  const float* ln3_w      = (const float*)d_in[21];
  const float* ln3_b      = (const float*)d_in[22];
  const float* w_out      = (const float*)d_in[23];
  const float* b_out      = (const float*)d_in[24];
  float* out = (float*)d_out;

  char* ws = (char*)d_ws;
  size_t off = 0;
  auto alloc = [&](size_t bytes) -> void* {
    void* p = ws + off;
    off += (bytes + 255) & ~(size_t)255;
    return p;
  };
  float* fx32  = (float*)alloc((size_t)BB * NN * CC * 4);          // 64 MiB
  bf16* xln    = (bf16*)alloc((size_t)BB * NN * CC * 2);           // 32 MiB
  bf16* xmid   = (bf16*)alloc((size_t)BB * NN * INNERC * 2);       // 32 MiB
  bf16* fxmid  = (bf16*)alloc((size_t)BB * NN * INNERC * 2);       // 32 MiB
  bf16* swb    = (bf16*)alloc((size_t)BB * NN * NHEADS * GG * 2);  // 64 MiB
  float* st_raw= (float*)alloc((size_t)BB * NHEADS * GG * DHD * 4);
  float* normb = (float*)alloc((size_t)BB * NHEADS * GG * 4);
  float* otb   = (float*)alloc((size_t)BB * NHEADS * GG * DHD * 4);
  (void)ws_size; (void)in_sizes; (void)n_in; (void)out_size;

  hipMemcpyAsync(fx32, fx_in, (size_t)BB * NN * CC * sizeof(float),
                 hipMemcpyDeviceToDevice, stream);

  for (int i = 0; i < LL; ++i) {
    ln_kernel<<<BB * NN, 256, 0, stream>>>(fx32, ln1_w + i * CC, ln1_b + i * CC, xln);
    conv3x3_kernel<<<BB * HH * (WWI / 16), 256, 0, stream>>>(
        xln, convfx_w + (size_t)i * 9 * CC * INNERC, convfx_b + i * INNERC, fxmid);
    conv3x3_kernel<<<BB * HH * (WWI / 16), 256, 0, stream>>>(
        xln, convx_w + (size_t)i * 9 * CC * INNERC, convx_b + i * INNERC, xmid);
    slice_softmax_kernel<<<BB * NN, 512, 0, stream>>>(
        xmid, slice_w + i * DHD * GG, slice_b + i * GG, temperature + i * NHEADS, swb);
    slice_reduce_kernel<<<BB * NHEADS * GG, 256, 0, stream>>>(fxmid, swb, st_raw, normb);
    attn_kernel<<<BB * NHEADS, 64, 0, stream>>>(
        st_raw, normb, wq + i * DHD * DHD, wk + i * DHD * DHD, wv + i * DHD * DHD, otb);
    deslice_proj_kernel<<<BB * NN / 4, 256, 0, stream>>>(
        otb, swb, wo + i * INNERC * CC, bo + i * CC, fx32);
    ln_kernel<<<BB * NN, 256, 0, stream>>>(fx32, ln2_w + i * CC, ln2_b + i * CC, xln);
    mlp_kernel<<<BB * NN / 8, 256, 0, stream>>>(
        xln, w1 + (size_t)i * CC * HIDD, b1 + i * HIDD, w2 + (size_t)i * HIDD * CC, b2 + i * CC, fx32);
  }
  head_kernel<<<BB * NN, 256, 0, stream>>>(fx32, ln3_w, ln3_b, w_out, b_out, out);
}

// Round 3
// 6587.070 us; speedup vs baseline: 3.5257x; 3.5257x over previous
//
#include <hip/hip_runtime.h>
#include <hip/hip_bf16.h>

typedef __hip_bfloat16 bf16;
typedef __bf16 bfv8 __attribute__((ext_vector_type(8)));
typedef float f32x4 __attribute__((ext_vector_type(4)));

#define BB 4
#define HH 128
#define WWI 128
#define NN 16384      // HH*WWI
#define CC 256
#define LL 4
#define NHEADS 8
#define DHD 32
#define GG 64
#define INNERC 256    // NHEADS*DHD
#define HIDD 1024

__device__ __forceinline__ float b2f(bf16 x) { return __bfloat162float(x); }
__device__ __forceinline__ bf16 f2b(float x) { return __float2bfloat16(x); }

__device__ __forceinline__ float wave_sum(float v) {
#pragma unroll
  for (int off = 32; off > 0; off >>= 1) v += __shfl_down(v, off, 64);
  return v;
}

__device__ __forceinline__ float gelu_exact(float x) {
  return 0.5f * x * (1.0f + erff(x * 0.70710678118654752f));
}

// ---------- batched transpose+cast: src fp32 [T][R][Cm] -> dst bf16 [T][Cm][R] ----------
__global__ void transpose_cast_kernel(const float* __restrict__ src, bf16* __restrict__ dst,
                                      int R, int Cm) {
  __shared__ float tile[32][33];
  int tb = blockIdx.z;
  const float* s = src + (size_t)tb * R * Cm;
  bf16* d = dst + (size_t)tb * R * Cm;
  int c0 = blockIdx.x * 32, r0 = blockIdx.y * 32;
  int tx = threadIdx.x & 31, ty = threadIdx.x >> 5;  // 32 x 8
  for (int rr = ty; rr < 32; rr += 8) {
    int r = r0 + rr, c = c0 + tx;
    tile[rr][tx] = (r < R && c < Cm) ? s[(size_t)r * Cm + c] : 0.f;
  }
  __syncthreads();
  for (int cc = ty; cc < 32; cc += 8) {
    int c = c0 + cc, r = r0 + tx;
    if (c < Cm && r < R) d[(size_t)c * R + r] = f2b(tile[tx][cc]);
  }
}

// ---------- LayerNorm over C=256 per point; block = 256 threads ----------
__global__ void ln_kernel(const float* __restrict__ x, const float* __restrict__ w,
                          const float* __restrict__ b, bf16* __restrict__ out) {
  int pp = blockIdx.x;
  int t = threadIdx.x;
  float v = x[(size_t)pp * CC + t];
  float s = wave_sum(v);
  float sq = wave_sum(v * v);
  __shared__ float ls[4], lq[4];
  int wid = t >> 6, lane = t & 63;
  if (lane == 0) { ls[wid] = s; lq[wid] = sq; }
  __syncthreads();
  float tot = ls[0] + ls[1] + ls[2] + ls[3];
  float totq = lq[0] + lq[1] + lq[2] + lq[3];
  float mean = tot * (1.0f / CC);
  float var = totq * (1.0f / CC) - mean * mean;
  float rstd = rsqrtf(var + 1e-5f);
  float o = (v - mean) * rstd * w[t] + b[t];
  out[(size_t)pp * CC + t] = f2b(o);
}

// ---------- 3x3 conv as implicit MFMA GEMM ----------
// Block: one image row (128 px) x 128 outch. wt: bf16 [9][256 o][256 c].
__global__ __launch_bounds__(256, 2) void conv_mfma_kernel(
    const bf16* __restrict__ xln, const bf16* __restrict__ wt,
    const float* __restrict__ bias, bf16* __restrict__ out) {
  __shared__ __align__(16) unsigned short As[3 * 130 * 64];  // [ky][cl 0..129][64 ch], swizzled
  __shared__ __align__(16) unsigned short Bsm[128 * 64];     // [o][64 ch], swizzled
  int bid = blockIdx.x;
  int nh = bid & 1;
  int h = (bid >> 1) & 127;
  int b = bid >> 8;
  int t = threadIdx.x, lane = t & 63, wid = t >> 6;
  int wm = (wid >> 1) * 64, wn = (wid & 1) * 64;
  int l15 = lane & 15, l4 = lane >> 4;
  f32x4 acc[4][4];
#pragma unroll
  for (int mi = 0; mi < 4; ++mi)
#pragma unroll
    for (int ni = 0; ni < 4; ++ni) acc[mi][ni] = (f32x4){0.f, 0.f, 0.f, 0.f};
  const bf16* xbase = xln + (size_t)b * NN * CC;

  for (int q = 0; q < 4; ++q) {           // channel chunks of 64
    __syncthreads();                      // previous chunk's compute done
    // stage A halo rows (h-1,h,h+1) x cols (-1..128) for chunk q
    for (int u = t; u < 3120; u += 256) {
      int jp = u & 7;
      int pc = u >> 3;                    // 0..389
      int r = pc / 130, cl = pc - r * 130;
      int j = jp ^ (cl & 7);
      int gr = h + r - 1, gc = cl - 1;
      uint4 v = make_uint4(0u, 0u, 0u, 0u);
      if ((unsigned)gr < 128u && (unsigned)gc < 128u)
        v = *(const uint4*)(xbase + ((size_t)(gr * WWI + gc)) * CC + q * 64 + j * 8);
      *(uint4*)(&As[(size_t)u * 8]) = v;
    }
    for (int tap = 0; tap < 9; ++tap) {
      if (tap > 0) __syncthreads();       // previous tap compute done before Bs overwrite
      {
        const bf16* wsrc = wt + ((size_t)tap * 256 + nh * 128) * 256 + q * 64;
#pragma unroll
        for (int i = 0; i < 4; ++i) {
          int u = t + (i << 8);
          int n = u >> 3, jp = u & 7, j = jp ^ (n & 7);
          uint4 v = *(const uint4*)(wsrc + (size_t)n * 256 + j * 8);
          *(uint4*)(&Bsm[(size_t)u * 8]) = v;
        }
      }
      __syncthreads();
      int ky = tap / 3, kx = tap - ky * 3;
#pragma unroll
      for (int s = 0; s < 2; ++s) {
        bfv8 af[4], bfr[4];
#pragma unroll
        for (int mi = 0; mi < 4; ++mi) {
          int cl = wm + mi * 16 + l15 + kx;
          af[mi] = *(const bfv8*)(&As[((size_t)(ky * 130 + cl)) * 64 +
                                      (((s * 4 + l4) ^ (cl & 7)) << 3)]);
        }
#pragma unroll
        for (int ni = 0; ni < 4; ++ni) {
          int rn = wn + ni * 16 + l15;
          bfr[ni] = *(const bfv8*)(&Bsm[(size_t)rn * 64 + (((s * 4 + l4) ^ (rn & 7)) << 3)]);
        }
#pragma unroll
        for (int mi = 0; mi < 4; ++mi)
#pragma unroll
          for (int ni = 0; ni < 4; ++ni)
            acc[mi][ni] = __builtin_amdgcn_mfma_f32_16x16x32_bf16(af[mi], bfr[ni], acc[mi][ni], 0, 0, 0);
      }
    }
  }
  // epilogue
  int colB = wn + l15;
  int rowB = wm + l4 * 4;
#pragma unroll
  for (int ni = 0; ni < 4; ++ni) {
    int oc = nh * 128 + colB + ni * 16;
    float bv = bias[oc];
#pragma unroll
    for (int mi = 0; mi < 4; ++mi) {
#pragma unroll
      for (int r = 0; r < 4; ++r) {
        int pix = rowB + mi * 16 + r;
        out[((size_t)(b * NN + h * WWI + pix)) * CC + oc] = f2b(acc[mi][ni][r] + bv);
      }
    }
  }
}

// ---------- generic MFMA GEMM: A[M,K] bf16, BT[N,K] bf16 ----------
// MODE 0: outb = bf16(gelu(acc+bias)); MODE 1: outf += acc+bias
template <int MODE>
__global__ __launch_bounds__(256, 2) void gemm_kernel(
    const bf16* __restrict__ A, const bf16* __restrict__ BT,
    const float* __restrict__ bias, bf16* __restrict__ outb,
    float* __restrict__ outf, int M, int N, int K) {
  __shared__ __align__(16) unsigned short As[128 * 64];
  __shared__ __align__(16) unsigned short Bsm[128 * 64];
  int m0 = blockIdx.x * 128, n0 = blockIdx.y * 128;
  int t = threadIdx.x, lane = t & 63, wid = t >> 6;
  int wm = (wid >> 1) * 64, wn = (wid & 1) * 64;
  int l15 = lane & 15, l4 = lane >> 4;
  f32x4 acc[4][4];
#pragma unroll
  for (int mi = 0; mi < 4; ++mi)
#pragma unroll
    for (int ni = 0; ni < 4; ++ni) acc[mi][ni] = (f32x4){0.f, 0.f, 0.f, 0.f};

  for (int kb = 0; kb < K; kb += 64) {
    __syncthreads();
    uint4 va[4], vb[4];
#pragma unroll
    for (int i = 0; i < 4; ++i) {
      int u = t + (i << 8);
      int row = u >> 3, j = (u & 7) ^ (row & 7);
      va[i] = *(const uint4*)(A + (size_t)(m0 + row) * K + kb + j * 8);
      vb[i] = *(const uint4*)(BT + (size_t)(n0 + row) * K + kb + j * 8);
    }
#pragma unroll
    for (int i = 0; i < 4; ++i) {
      int u = t + (i << 8);
      *(uint4*)(&As[(size_t)u * 8]) = va[i];
      *(uint4*)(&Bsm[(size_t)u * 8]) = vb[i];
    }
    __syncthreads();
#pragma unroll
    for (int s = 0; s < 2; ++s) {
      bfv8 af[4], bfr[4];
#pragma unroll
      for (int mi = 0; mi < 4; ++mi) {
        int row = wm + mi * 16 + l15;
        af[mi] = *(const bfv8*)(&As[(size_t)row * 64 + (((s * 4 + l4) ^ (row & 7)) << 3)]);
      }
#pragma unroll
      for (int ni = 0; ni < 4; ++ni) {
        int rn = wn + ni * 16 + l15;
        bfr[ni] = *(const bfv8*)(&Bsm[(size_t)rn * 64 + (((s * 4 + l4) ^ (rn & 7)) << 3)]);
      }
#pragma unroll
      for (int mi = 0; mi < 4; ++mi)
#pragma unroll
        for (int ni = 0; ni < 4; ++ni)
          acc[mi][ni] = __builtin_amdgcn_mfma_f32_16x16x32_bf16(af[mi], bfr[ni], acc[mi][ni], 0, 0, 0);
    }
  }
  int colB = n0 + wn + l15;
  int rowB = m0 + wm + l4 * 4;
#pragma unroll
  for (int ni = 0; ni < 4; ++ni) {
    int col = colB + ni * 16;
    float bv = bias[col];
#pragma unroll
    for (int mi = 0; mi < 4; ++mi) {
#pragma unroll
      for (int r = 0; r < 4; ++r) {
        int row = rowB + mi * 16 + r;
        float v = acc[mi][ni][r] + bv;
        if (MODE == 0) outb[(size_t)row * N + col] = f2b(gelu_exact(v));
        else outf[(size_t)row * N + col] += v;
      }
    }
  }
}

// ---------- slice logits + softmax over G; block = 512 = 8 heads x 64 g ----------
__global__ void slice_softmax_kernel(const bf16* __restrict__ xmid, const float* __restrict__ sw_w,
                                     const float* __restrict__ sw_b, const float* __restrict__ temp,
                                     bf16* __restrict__ swout) {
  __shared__ float xm[CC];
  int pp = blockIdx.x;
  int t = threadIdx.x;   // 512
  if (t < CC) xm[t] = b2f(xmid[(size_t)pp * CC + t]);
  __syncthreads();
  int h = t >> 6, g = t & 63;
  float acc = sw_b[g];
  const float* xp = &xm[h * DHD];
#pragma unroll
  for (int d = 0; d < DHD; ++d)
    acc += xp[d] * sw_w[d * GG + g];
  float tc = temp[h];
  tc = fminf(fmaxf(tc, 0.1f), 5.0f);
  float logit = acc / tc;
  float m = logit;
#pragma unroll
  for (int off = 32; off > 0; off >>= 1) m = fmaxf(m, __shfl_xor(m, off, 64));
  float e = __expf(logit - m);
  float s = e;
#pragma unroll
  for (int off = 32; off > 0; off >>= 1) s += __shfl_xor(s, off, 64);
  swout[(size_t)pp * (NHEADS * GG) + t] = f2b(e / s);
}

// ---------- st_raw[b,h,g,:] = sum_n fxmid*sw ; norm[b,h,g] = sum_n sw ----------
__global__ void slice_reduce_kernel(const bf16* __restrict__ fxmid, const bf16* __restrict__ sw,
                                    float* __restrict__ st_raw, float* __restrict__ normbuf) {
  int blk = blockIdx.x;   // B*8*64
  int g = blk & 63;
  int h = (blk >> 6) & 7;
  int b = blk >> 9;
  int t = threadIdx.x;    // 256
  int sub = t >> 5, d = t & 31;
  float acc = 0.0f, nacc = 0.0f;
  const bf16* swp = sw + ((size_t)b * NN) * (NHEADS * GG) + h * GG + g;
  const bf16* fxp = fxmid + ((size_t)b * NN) * INNERC + h * DHD + d;
  for (int n = sub; n < NN; n += 8) {
    float s = b2f(swp[(size_t)n * (NHEADS * GG)]);
    float f = b2f(fxp[(size_t)n * INNERC]);
    acc += f * s;
    nacc += s;
  }
  __shared__ float red[8][32];
  __shared__ float nred[8];
  red[sub][d] = acc;
  if (d == 0) nred[sub] = nacc;
  __syncthreads();
  if (sub == 0) {
    float tot = 0.0f;
#pragma unroll
    for (int s2 = 0; s2 < 8; ++s2) tot += red[s2][d];
    st_raw[(size_t)blk * DHD + d] = tot;
    if (d == 0) {
      float nt = 0.0f;
#pragma unroll
      for (int s2 = 0; s2 < 8; ++s2) nt += nred[s2];
      normbuf[blk] = nt;
    }
  }
}

// ---------- tiny attention over G=64 tokens, per (b,h); block = 64 threads ----------
__global__ void attn_kernel(const float* __restrict__ st_raw, const float* __restrict__ normbuf,
                            const float* __restrict__ wq, const float* __restrict__ wk,
                            const float* __restrict__ wv, float* __restrict__ ot) {
  int bh = blockIdx.x;     // B*8
  int g = threadIdx.x;     // 64
  __shared__ float st[GG][DHD], kk[GG][DHD], vv[GG][DHD];
  float rn = 1.0f / (normbuf[bh * GG + g] + 1e-5f);
#pragma unroll
  for (int d = 0; d < DHD; ++d)
    st[g][d] = st_raw[((size_t)bh * GG + g) * DHD + d] * rn;
  __syncthreads();
  float q[DHD];
#pragma unroll
  for (int d = 0; d < DHD; ++d) {
    float aq = 0, ak = 0, av = 0;
#pragma unroll
    for (int c = 0; c < DHD; ++c) {
      float sv = st[g][c];
      aq += sv * wq[c * DHD + d];
      ak += sv * wk[c * DHD + d];
      av += sv * wv[c * DHD + d];
    }
    q[d] = aq; kk[g][d] = ak; vv[g][d] = av;
  }
  __syncthreads();
  float sc[GG];
  float m = -1e30f;
  const float scale = 0.17677669529663687f;   // 1/sqrt(32)
#pragma unroll
  for (int j = 0; j < GG; ++j) {
    float a = 0;
#pragma unroll
    for (int d = 0; d < DHD; ++d) a += q[d] * kk[j][d];
    a *= scale;
    sc[j] = a;
    m = fmaxf(m, a);
  }
  float s = 0;
#pragma unroll
  for (int j = 0; j < GG; ++j) { sc[j] = __expf(sc[j] - m); s += sc[j]; }
  float rs = 1.0f / s;
#pragma unroll
  for (int d = 0; d < DHD; ++d) {
    float a = 0;
#pragma unroll
    for (int j = 0; j < GG; ++j) a += sc[j] * vv[j][d];
    ot[((size_t)bh * GG + g) * DHD + d] = a * rs;
  }
}

// ---------- deslice: out_x[p, h*32+d] = sum_g ot[b,h,g,d]*sw[p,h*64+g] ----------
__global__ void deslice_kernel(const float* __restrict__ ot, const bf16* __restrict__ sw,
                               bf16* __restrict__ outx) {
  int pp = blockIdx.x;          // b*N + n
  int b = pp >> 14;
  int t = threadIdx.x;          // 256
  __shared__ float swl[NHEADS * GG];
  swl[t] = b2f(sw[(size_t)pp * 512 + t]);
  swl[t + 256] = b2f(sw[(size_t)pp * 512 + t + 256]);
  __syncthreads();
  int hh = t >> 5, d = t & 31;
  const float* otp = ot + ((size_t)(b * NHEADS + hh) * GG) * DHD + d;
  const float* swh = &swl[hh * GG];
  float a = 0.f;
#pragma unroll 8
  for (int g = 0; g < GG; ++g) a += otp[(size_t)g * DHD] * swh[g];
  outx[(size_t)pp * INNERC + t] = f2b(a);
}

// ---------- final LN3 + head (C -> 4) ----------
__global__ void head_kernel(const float* __restrict__ fx, const float* __restrict__ w,
                            const float* __restrict__ b, const float* __restrict__ wout,
                            const float* __restrict__ bout, float* __restrict__ out) {
  int pp = blockIdx.x;
  int t = threadIdx.x;
  float v = fx[(size_t)pp * CC + t];
  float s = wave_sum(v);
  float sq = wave_sum(v * v);
  __shared__ float ls[4], lq[4];
  int wid = t >> 6, lane = t & 63;
  if (lane == 0) { ls[wid] = s; lq[wid] = sq; }
  __syncthreads();
  float tot = ls[0] + ls[1] + ls[2] + ls[3];
  float totq = lq[0] + lq[1] + lq[2] + lq[3];
  float mean = tot * (1.0f / CC);
  float var = totq * (1.0f / CC) - mean * mean;
  float rstd = rsqrtf(var + 1e-5f);
  float xn = (v - mean) * rstd * w[t] + b[t];
  __shared__ float xs[CC];
  xs[t] = xn;
  __syncthreads();
  if (t < 4) {
    float a = bout[t];
    for (int c = 0; c < CC; ++c) a += xs[c] * wout[c * 4 + t];
    out[(size_t)pp * 4 + t] = a;
  }
}

extern "C" void kernel_launch(void* const* d_in, const int* in_sizes, int n_in,
                              void* d_out, int out_size, void* d_ws, size_t ws_size,
                              hipStream_t stream) {
  const float* fx_in      = (const float*)d_in[0];
  const float* ln1_w      = (const float*)d_in[1];
  const float* ln1_b      = (const float*)d_in[2];
  const float* convx_w    = (const float*)d_in[3];
  const float* convx_b    = (const float*)d_in[4];
  const float* convfx_w   = (const float*)d_in[5];
  const float* convfx_b   = (const float*)d_in[6];
  const float* slice_w    = (const float*)d_in[7];
  const float* slice_b    = (const float*)d_in[8];
  const float* temperature= (const float*)d_in[9];
  const float* wq         = (const float*)d_in[10];
  const float* wk         = (const float*)d_in[11];
  const float* wv         = (const float*)d_in[12];
  const float* wo         = (const float*)d_in[13];
  const float* bo         = (const float*)d_in[14];
  const float* ln2_w      = (const float*)d_in[15];
  const float* ln2_b      = (const float*)d_in[16];
  const float* w1         = (const float*)d_in[17];
  const float* b1         = (const float*)d_in[18];
  const float* w2         = (const float*)d_in[19];
  const float* b2         = (const float*)d_in[20];
  const float* ln3_w      = (const float*)d_in[21];
  const float* ln3_b      = (const float*)d_in[22];
  const float* w_out      = (const float*)d_in[23];
  const float* b_out      = (const float*)d_in[24];
  float* out = (float*)d_out;

  char* ws = (char*)d_ws;
  size_t off = 0;
  auto alloc = [&](size_t bytes) -> void* {
    void* p = ws + off;
    off += (bytes + 255) & ~(size_t)255;
    return p;
  };
  float* fx32  = (float*)alloc((size_t)BB * NN * CC * 4);    // 64 MiB
  bf16* xln    = (bf16*)alloc((size_t)BB * NN * CC * 2);     // 32 MiB
  char* uni    = (char*)alloc((size_t)BB * NN * HIDD * 2);   // 128 MiB union region
  bf16* xmid   = (bf16*)uni;                                  // 32 MiB
  bf16* fxmid  = (bf16*)(uni + (size_t)BB * NN * INNERC * 2); // 32 MiB
  bf16* swb    = (bf16*)(uni + (size_t)2 * BB * NN * INNERC * 2); // 64 MiB
  bf16* hidden = (bf16*)uni;                                  // aliases all three (dead by MLP)
  bf16* outx   = (bf16*)uni;                                  // aliases xmid (dead by deslice)
  bf16* wtx    = (bf16*)alloc((size_t)LL * 9 * CC * INNERC * 2);
  bf16* wtfx   = (bf16*)alloc((size_t)LL * 9 * CC * INNERC * 2);
  bf16* w1t    = (bf16*)alloc((size_t)LL * CC * HIDD * 2);
  bf16* w2t    = (bf16*)alloc((size_t)LL * HIDD * CC * 2);
  bf16* wot    = (bf16*)alloc((size_t)LL * INNERC * CC * 2);
  float* st_raw= (float*)alloc((size_t)BB * NHEADS * GG * DHD * 4);
  float* normb = (float*)alloc((size_t)BB * NHEADS * GG * 4);
  float* otb   = (float*)alloc((size_t)BB * NHEADS * GG * DHD * 4);
  (void)ws_size; (void)in_sizes; (void)n_in; (void)out_size;

  // ---- weight prep: transpose + bf16 cast ----
  transpose_cast_kernel<<<dim3(8, 8, LL * 9), 256, 0, stream>>>(convx_w, wtx, CC, INNERC);
  transpose_cast_kernel<<<dim3(8, 8, LL * 9), 256, 0, stream>>>(convfx_w, wtfx, CC, INNERC);
  transpose_cast_kernel<<<dim3(32, 8, LL), 256, 0, stream>>>(w1, w1t, CC, HIDD);
  transpose_cast_kernel<<<dim3(8, 32, LL), 256, 0, stream>>>(w2, w2t, HIDD, CC);
  transpose_cast_kernel<<<dim3(8, 8, LL), 256, 0, stream>>>(wo, wot, INNERC, CC);

  hipMemcpyAsync(fx32, fx_in, (size_t)BB * NN * CC * sizeof(float),
                 hipMemcpyDeviceToDevice, stream);

  const int M = BB * NN;  // 65536
  for (int i = 0; i < LL; ++i) {
    ln_kernel<<<M, 256, 0, stream>>>(fx32, ln1_w + i * CC, ln1_b + i * CC, xln);
    conv_mfma_kernel<<<BB * HH * 2, 256, 0, stream>>>(
        xln, wtfx + (size_t)i * 9 * CC * INNERC, convfx_b + i * INNERC, fxmid);
    conv_mfma_kernel<<<BB * HH * 2, 256, 0, stream>>>(
        xln, wtx + (size_t)i * 9 * CC * INNERC, convx_b + i * INNERC, xmid);
    slice_softmax_kernel<<<M, 512, 0, stream>>>(
        xmid, slice_w + i * DHD * GG, slice_b + i * GG, temperature + i * NHEADS, swb);
    slice_reduce_kernel<<<BB * NHEADS * GG, 256, 0, stream>>>(fxmid, swb, st_raw, normb);
    attn_kernel<<<BB * NHEADS, 64, 0, stream>>>(
        st_raw, normb, wq + i * DHD * DHD, wk + i * DHD * DHD, wv + i * DHD * DHD, otb);
    deslice_kernel<<<M, 256, 0, stream>>>(otb, swb, outx);
    gemm_kernel<1><<<dim3(M / 128, CC / 128), 256, 0, stream>>>(
        outx, wot + (size_t)i * INNERC * CC, bo + i * CC, nullptr, fx32, M, CC, INNERC);
    ln_kernel<<<M, 256, 0, stream>>>(fx32, ln2_w + i * CC, ln2_b + i * CC, xln);
    gemm_kernel<0><<<dim3(M / 128, HIDD / 128), 256, 0, stream>>>(
        xln, w1t + (size_t)i * CC * HIDD, b1 + i * HIDD, hidden, nullptr, M, HIDD, CC);
    gemm_kernel<1><<<dim3(M / 128, CC / 128), 256, 0, stream>>>(
        hidden, w2t + (size_t)i * HIDD * CC, b2 + i * CC, nullptr, fx32, M, CC, HIDD);
  }
  head_kernel<<<M, 256, 0, stream>>>(fx32, ln3_w, ln3_b, w_out, b_out, out);
}

// Round 4
// 4401.728 us; speedup vs baseline: 5.2761x; 1.4965x over previous
//
#include <hip/hip_runtime.h>
#include <hip/hip_bf16.h>

typedef __hip_bfloat16 bf16;
typedef __bf16 bfv8 __attribute__((ext_vector_type(8)));
typedef float f32x4 __attribute__((ext_vector_type(4)));

#define BB 4
#define HH 128
#define WWI 128
#define NN 16384      // HH*WWI
#define CC 256
#define LL 4
#define NHEADS 8
#define DHD 32
#define GG 64
#define INNERC 256    // NHEADS*DHD
#define HIDD 1024
#define SPLIT 32      // split-K blocks per (b,h) in slice_st

__device__ __forceinline__ float b2f(bf16 x) { return __bfloat162float(x); }
__device__ __forceinline__ bf16 f2b(float x) { return __float2bfloat16(x); }
__device__ __forceinline__ float us2f(unsigned short v) {
  return __uint_as_float(((unsigned)v) << 16);
}

__device__ __forceinline__ float wave_sum(float v) {
#pragma unroll
  for (int off = 32; off > 0; off >>= 1) v += __shfl_down(v, off, 64);
  return v;
}

__device__ __forceinline__ float gelu_exact(float x) {
  return 0.5f * x * (1.0f + erff(x * 0.70710678118654752f));
}

// ---------- batched transpose+cast: src fp32 [T][R][Cm] -> dst bf16 [T][Cm][R] ----------
__global__ void transpose_cast_kernel(const float* __restrict__ src, bf16* __restrict__ dst,
                                      int R, int Cm) {
  __shared__ float tile[32][33];
  int tb = blockIdx.z;
  const float* s = src + (size_t)tb * R * Cm;
  bf16* d = dst + (size_t)tb * R * Cm;
  int c0 = blockIdx.x * 32, r0 = blockIdx.y * 32;
  int tx = threadIdx.x & 31, ty = threadIdx.x >> 5;  // 32 x 8
  for (int rr = ty; rr < 32; rr += 8) {
    int r = r0 + rr, c = c0 + tx;
    tile[rr][tx] = (r < R && c < Cm) ? s[(size_t)r * Cm + c] : 0.f;
  }
  __syncthreads();
  for (int cc = ty; cc < 32; cc += 8) {
    int c = c0 + cc, r = r0 + tx;
    if (c < Cm && r < R) d[(size_t)c * R + r] = f2b(tile[tx][cc]);
  }
}

// ---------- LayerNorm over C=256 per point; block = 256 threads ----------
__global__ void ln_kernel(const float* __restrict__ x, const float* __restrict__ w,
                          const float* __restrict__ b, bf16* __restrict__ out) {
  int pp = blockIdx.x;
  int t = threadIdx.x;
  float v = x[(size_t)pp * CC + t];
  float s = wave_sum(v);
  float sq = wave_sum(v * v);
  __shared__ float ls[4], lq[4];
  int wid = t >> 6, lane = t & 63;
  if (lane == 0) { ls[wid] = s; lq[wid] = sq; }
  __syncthreads();
  float tot = ls[0] + ls[1] + ls[2] + ls[3];
  float totq = lq[0] + lq[1] + lq[2] + lq[3];
  float mean = tot * (1.0f / CC);
  float var = totq * (1.0f / CC) - mean * mean;
  float rstd = rsqrtf(var + 1e-5f);
  float o = (v - mean) * rstd * w[t] + b[t];
  out[(size_t)pp * CC + t] = f2b(o);
}

// ---------- 3x3 conv as implicit MFMA GEMM ----------
// Block: one image row (128 px) x 128 outch. wt: bf16 [9][256 o][256 c].
__global__ __launch_bounds__(256, 2) void conv_mfma_kernel(
    const bf16* __restrict__ xln, const bf16* __restrict__ wt,
    const float* __restrict__ bias, bf16* __restrict__ out) {
  __shared__ __align__(16) unsigned short As[3 * 130 * 64];  // [ky][cl 0..129][64 ch], swizzled
  __shared__ __align__(16) unsigned short Bsm[128 * 64];     // [o][64 ch], swizzled
  int bid = blockIdx.x;
  int nh = bid & 1;
  int h = (bid >> 1) & 127;
  int b = bid >> 8;
  int t = threadIdx.x, lane = t & 63, wid = t >> 6;
  int wm = (wid >> 1) * 64, wn = (wid & 1) * 64;
  int l15 = lane & 15, l4 = lane >> 4;
  f32x4 acc[4][4];
#pragma unroll
  for (int mi = 0; mi < 4; ++mi)
#pragma unroll
    for (int ni = 0; ni < 4; ++ni) acc[mi][ni] = (f32x4){0.f, 0.f, 0.f, 0.f};
  const bf16* xbase = xln + (size_t)b * NN * CC;

  for (int q = 0; q < 4; ++q) {           // channel chunks of 64
    __syncthreads();                      // previous chunk's compute done
    // stage A halo rows (h-1,h,h+1) x cols (-1..128) for chunk q
    for (int u = t; u < 3120; u += 256) {
      int jp = u & 7;
      int pc = u >> 3;                    // 0..389
      int r = pc / 130, cl = pc - r * 130;
      int j = jp ^ (cl & 7);
      int gr = h + r - 1, gc = cl - 1;
      uint4 v = make_uint4(0u, 0u, 0u, 0u);
      if ((unsigned)gr < 128u && (unsigned)gc < 128u)
        v = *(const uint4*)(xbase + ((size_t)(gr * WWI + gc)) * CC + q * 64 + j * 8);
      *(uint4*)(&As[(size_t)u * 8]) = v;
    }
    for (int tap = 0; tap < 9; ++tap) {
      if (tap > 0) __syncthreads();       // previous tap compute done before Bs overwrite
      {
        const bf16* wsrc = wt + ((size_t)tap * 256 + nh * 128) * 256 + q * 64;
#pragma unroll
        for (int i = 0; i < 4; ++i) {
          int u = t + (i << 8);
          int n = u >> 3, jp = u & 7, j = jp ^ (n & 7);
          uint4 v = *(const uint4*)(wsrc + (size_t)n * 256 + j * 8);
          *(uint4*)(&Bsm[(size_t)u * 8]) = v;
        }
      }
      __syncthreads();
      int ky = tap / 3, kx = tap - ky * 3;
#pragma unroll
      for (int s = 0; s < 2; ++s) {
        bfv8 af[4], bfr[4];
#pragma unroll
        for (int mi = 0; mi < 4; ++mi) {
          int cl = wm + mi * 16 + l15 + kx;
          af[mi] = *(const bfv8*)(&As[((size_t)(ky * 130 + cl)) * 64 +
                                      (((s * 4 + l4) ^ (cl & 7)) << 3)]);
        }
#pragma unroll
        for (int ni = 0; ni < 4; ++ni) {
          int rn = wn + ni * 16 + l15;
          bfr[ni] = *(const bfv8*)(&Bsm[(size_t)rn * 64 + (((s * 4 + l4) ^ (rn & 7)) << 3)]);
        }
#pragma unroll
        for (int mi = 0; mi < 4; ++mi)
#pragma unroll
          for (int ni = 0; ni < 4; ++ni)
            acc[mi][ni] = __builtin_amdgcn_mfma_f32_16x16x32_bf16(af[mi], bfr[ni], acc[mi][ni], 0, 0, 0);
      }
    }
  }
  // epilogue
  int colB = wn + l15;
  int rowB = wm + l4 * 4;
#pragma unroll
  for (int ni = 0; ni < 4; ++ni) {
    int oc = nh * 128 + colB + ni * 16;
    float bv = bias[oc];
#pragma unroll
    for (int mi = 0; mi < 4; ++mi) {
#pragma unroll
      for (int r = 0; r < 4; ++r) {
        int pix = rowB + mi * 16 + r;
        out[((size_t)(b * NN + h * WWI + pix)) * CC + oc] = f2b(acc[mi][ni][r] + bv);
      }
    }
  }
}

// ---------- generic MFMA GEMM: A[M,K] bf16, BT[N,K] bf16 ----------
// MODE 0: outb = bf16(gelu(acc+bias)); MODE 1: outf += acc+bias
template <int MODE>
__global__ __launch_bounds__(256, 2) void gemm_kernel(
    const bf16* __restrict__ A, const bf16* __restrict__ BT,
    const float* __restrict__ bias, bf16* __restrict__ outb,
    float* __restrict__ outf, int M, int N, int K) {
  __shared__ __align__(16) unsigned short As[128 * 64];
  __shared__ __align__(16) unsigned short Bsm[128 * 64];
  int m0 = blockIdx.x * 128, n0 = blockIdx.y * 128;
  int t = threadIdx.x, lane = t & 63, wid = t >> 6;
  int wm = (wid >> 1) * 64, wn = (wid & 1) * 64;
  int l15 = lane & 15, l4 = lane >> 4;
  f32x4 acc[4][4];
#pragma unroll
  for (int mi = 0; mi < 4; ++mi)
#pragma unroll
    for (int ni = 0; ni < 4; ++ni) acc[mi][ni] = (f32x4){0.f, 0.f, 0.f, 0.f};

  for (int kb = 0; kb < K; kb += 64) {
    __syncthreads();
    uint4 va[4], vb[4];
#pragma unroll
    for (int i = 0; i < 4; ++i) {
      int u = t + (i << 8);
      int row = u >> 3, j = (u & 7) ^ (row & 7);
      va[i] = *(const uint4*)(A + (size_t)(m0 + row) * K + kb + j * 8);
      vb[i] = *(const uint4*)(BT + (size_t)(n0 + row) * K + kb + j * 8);
    }
#pragma unroll
    for (int i = 0; i < 4; ++i) {
      int u = t + (i << 8);
      *(uint4*)(&As[(size_t)u * 8]) = va[i];
      *(uint4*)(&Bsm[(size_t)u * 8]) = vb[i];
    }
    __syncthreads();
#pragma unroll
    for (int s = 0; s < 2; ++s) {
      bfv8 af[4], bfr[4];
#pragma unroll
      for (int mi = 0; mi < 4; ++mi) {
        int row = wm + mi * 16 + l15;
        af[mi] = *(const bfv8*)(&As[(size_t)row * 64 + (((s * 4 + l4) ^ (row & 7)) << 3)]);
      }
#pragma unroll
      for (int ni = 0; ni < 4; ++ni) {
        int rn = wn + ni * 16 + l15;
        bfr[ni] = *(const bfv8*)(&Bsm[(size_t)rn * 64 + (((s * 4 + l4) ^ (rn & 7)) << 3)]);
      }
#pragma unroll
      for (int mi = 0; mi < 4; ++mi)
#pragma unroll
        for (int ni = 0; ni < 4; ++ni)
          acc[mi][ni] = __builtin_amdgcn_mfma_f32_16x16x32_bf16(af[mi], bfr[ni], acc[mi][ni], 0, 0, 0);
    }
  }
  int colB = n0 + wn + l15;
  int rowB = m0 + wm + l4 * 4;
#pragma unroll
  for (int ni = 0; ni < 4; ++ni) {
    int col = colB + ni * 16;
    float bv = bias[col];
#pragma unroll
    for (int mi = 0; mi < 4; ++mi) {
#pragma unroll
      for (int r = 0; r < 4; ++r) {
        int row = rowB + mi * 16 + r;
        float v = acc[mi][ni][r] + bv;
        if (MODE == 0) outb[(size_t)row * N + col] = f2b(gelu_exact(v));
        else outf[(size_t)row * N + col] += v;
      }
    }
  }
}

// ---------- slice logits + softmax over G; block = 512 = 8 heads x 64 g ----------
__global__ void slice_softmax_kernel(const bf16* __restrict__ xmid, const float* __restrict__ sw_w,
                                     const float* __restrict__ sw_b, const float* __restrict__ temp,
                                     bf16* __restrict__ swout) {
  __shared__ float xm[CC];
  int pp = blockIdx.x;
  int t = threadIdx.x;   // 512
  if (t < CC) xm[t] = b2f(xmid[(size_t)pp * CC + t]);
  __syncthreads();
  int h = t >> 6, g = t & 63;
  float acc = sw_b[g];
  const float* xp = &xm[h * DHD];
#pragma unroll
  for (int d = 0; d < DHD; ++d)
    acc += xp[d] * sw_w[d * GG + g];
  float tc = temp[h];
  tc = fminf(fmaxf(tc, 0.1f), 5.0f);
  float logit = acc / tc;
  float m = logit;
#pragma unroll
  for (int off = 32; off > 0; off >>= 1) m = fmaxf(m, __shfl_xor(m, off, 64));
  float e = __expf(logit - m);
  float s = e;
#pragma unroll
  for (int off = 32; off > 0; off >>= 1) s += __shfl_xor(s, off, 64);
  swout[(size_t)pp * (NHEADS * GG) + t] = f2b(e / s);
}

// ---------- slice reduce as split-K MFMA outer product ----------
// stp[s][bh][g][d] = sum_{n in split s} sw[b,n,h*64+g] * fxmid[b,n,h*32+d]
// normp[s][bh][g]  = sum_{n in split s} sw[b,n,h*64+g]
__global__ __launch_bounds__(256) void slice_st_kernel(
    const bf16* __restrict__ fxmid, const bf16* __restrict__ sw,
    float* __restrict__ stp, float* __restrict__ normp) {
  __shared__ __align__(16) unsigned short sw_s[64 * 64];  // [g][n], xor-swizzled 16B units
  __shared__ __align__(16) unsigned short fx_s[32 * 64];  // [d][n], xor-swizzled
  __shared__ float npart[2][64];
  int split = blockIdx.x, h = blockIdx.y, b = blockIdx.z;
  int t = threadIdx.x, w = t >> 6, lane = t & 63;
  int l15 = lane & 15, q4 = lane >> 4;
  int ns0 = split * (NN / SPLIT);          // 512 n per block
  const int NT = (NN / SPLIT) / 64;        // 8 K-tiles of 64
  f32x4 acc0 = {0.f, 0.f, 0.f, 0.f}, acc1 = {0.f, 0.f, 0.f, 0.f};
  float nacc = 0.f;
  const unsigned short* swg = (const unsigned short*)sw + (size_t)b * NN * 512 + h * 64;
  const unsigned short* fxg = (const unsigned short*)fxmid + (size_t)b * NN * 256 + h * 32;

  for (int kt = 0; kt < NT; ++kt) {
    int n0 = ns0 + kt * 64;
    __syncthreads();                       // previous tile's MFMA done
    if (w < 2) {
      int g = lane;
#pragma unroll
      for (int i = 0; i < 4; ++i) {
        int j = w + 2 * i;                 // n-group of 8
        const unsigned short* p = swg + (size_t)(n0 + j * 8) * 512 + g;
        unsigned short v0 = p[0],     v1 = p[512],  v2 = p[1024], v3 = p[1536];
        unsigned short v4 = p[2048],  v5 = p[2560], v6 = p[3072], v7 = p[3584];
        nacc += us2f(v0) + us2f(v1) + us2f(v2) + us2f(v3) +
                us2f(v4) + us2f(v5) + us2f(v6) + us2f(v7);
        uint4 pk = make_uint4((unsigned)v0 | ((unsigned)v1 << 16),
                              (unsigned)v2 | ((unsigned)v3 << 16),
                              (unsigned)v4 | ((unsigned)v5 << 16),
                              (unsigned)v6 | ((unsigned)v7 << 16));
        ((uint4*)sw_s)[g * 8 + (j ^ (g & 7))] = pk;
      }
    } else {
      int d = lane & 31, nh = lane >> 5, w3 = w - 2;
#pragma unroll
      for (int i = 0; i < 2; ++i) {
        int nbase = (w3 * 2 + i) * 16 + nh * 8;
        const unsigned short* p = fxg + (size_t)(n0 + nbase) * 256 + d;
        unsigned short v0 = p[0],    v1 = p[256],  v2 = p[512],  v3 = p[768];
        unsigned short v4 = p[1024], v5 = p[1280], v6 = p[1536], v7 = p[1792];
        uint4 pk = make_uint4((unsigned)v0 | ((unsigned)v1 << 16),
                              (unsigned)v2 | ((unsigned)v3 << 16),
                              (unsigned)v4 | ((unsigned)v5 << 16),
                              (unsigned)v6 | ((unsigned)v7 << 16));
        int u = nbase >> 3;                // 0..7
        ((uint4*)fx_s)[d * 8 + (u ^ (d & 7))] = pk;
      }
    }
    __syncthreads();
    int gg = w * 16 + l15;
    int d0 = l15, d1 = 16 + l15;
#pragma unroll
    for (int ks = 0; ks < 2; ++ks) {
      bfv8 af  = ((const bfv8*)sw_s)[gg * 8 + ((ks * 4 + q4) ^ (gg & 7))];
      bfv8 bf0 = ((const bfv8*)fx_s)[d0 * 8 + ((ks * 4 + q4) ^ (d0 & 7))];
      bfv8 bf1 = ((const bfv8*)fx_s)[d1 * 8 + ((ks * 4 + q4) ^ (d1 & 7))];
      acc0 = __builtin_amdgcn_mfma_f32_16x16x32_bf16(af, bf0, acc0, 0, 0, 0);
      acc1 = __builtin_amdgcn_mfma_f32_16x16x32_bf16(af, bf1, acc1, 0, 0, 0);
    }
  }
  if (w < 2) npart[w][lane] = nacc;
  __syncthreads();
  int bh = b * NHEADS + h;
  if (t < 64) normp[(size_t)split * (BB * NHEADS * GG) + bh * 64 + t] = npart[0][t] + npart[1][t];
  size_t base = ((size_t)split * (BB * NHEADS * GG) + bh * 64) * 32;
#pragma unroll
  for (int r = 0; r < 4; ++r) {
    int g = w * 16 + q4 * 4 + r;
    stp[base + (size_t)g * 32 + l15] = acc0[r];
    stp[base + (size_t)g * 32 + 16 + l15] = acc1[r];
  }
}

// ---------- tiny attention over G=64 tokens, per (b,h); block = 64 threads ----------
// Also folds the SPLIT-way partial reduction of stp/normp.
__global__ void attn_kernel(const float* __restrict__ stp, const float* __restrict__ normp,
                            const float* __restrict__ wq, const float* __restrict__ wk,
                            const float* __restrict__ wv, float* __restrict__ ot) {
  int bh = blockIdx.x;     // B*8
  int g = threadIdx.x;     // 64
  __shared__ float st[GG][DHD], kk[GG][DHD], vv[GG][DHD];
  float nsum = 0.f;
  for (int s = 0; s < SPLIT; ++s)
    nsum += normp[(size_t)s * (BB * NHEADS * GG) + bh * 64 + g];
  float stl[DHD];
#pragma unroll
  for (int d = 0; d < DHD; ++d) stl[d] = 0.f;
  for (int s = 0; s < SPLIT; ++s) {
    const f32x4* p = (const f32x4*)(stp + ((size_t)s * (BB * NHEADS * GG) + bh * 64 + g) * 32);
#pragma unroll
    for (int d4 = 0; d4 < 8; ++d4) {
      f32x4 v = p[d4];
      stl[d4 * 4 + 0] += v[0]; stl[d4 * 4 + 1] += v[1];
      stl[d4 * 4 + 2] += v[2]; stl[d4 * 4 + 3] += v[3];
    }
  }
  float rn = 1.0f / (nsum + 1e-5f);
#pragma unroll
  for (int d = 0; d < DHD; ++d) st[g][d] = stl[d] * rn;
  __syncthreads();
  float q[DHD];
#pragma unroll
  for (int d = 0; d < DHD; ++d) {
    float aq = 0, ak = 0, av = 0;
#pragma unroll
    for (int c = 0; c < DHD; ++c) {
      float sv = st[g][c];
      aq += sv * wq[c * DHD + d];
      ak += sv * wk[c * DHD + d];
      av += sv * wv[c * DHD + d];
    }
    q[d] = aq; kk[g][d] = ak; vv[g][d] = av;
  }
  __syncthreads();
  float sc[GG];
  float m = -1e30f;
  const float scale = 0.17677669529663687f;   // 1/sqrt(32)
#pragma unroll
  for (int j = 0; j < GG; ++j) {
    float a = 0;
#pragma unroll
    for (int d = 0; d < DHD; ++d) a += q[d] * kk[j][d];
    a *= scale;
    sc[j] = a;
    m = fmaxf(m, a);
  }
  float s = 0;
#pragma unroll
  for (int j = 0; j < GG; ++j) { sc[j] = __expf(sc[j] - m); s += sc[j]; }
  float rs = 1.0f / s;
#pragma unroll
  for (int d = 0; d < DHD; ++d) {
    float a = 0;
#pragma unroll
    for (int j = 0; j < GG; ++j) a += sc[j] * vv[j][d];
    ot[((size_t)bh * GG + g) * DHD + d] = a * rs;
  }
}

// ---------- deslice: out_x[p, h*32+d] = sum_g ot[b,h,g,d]*sw[p,h*64+g] ----------
__global__ void deslice_kernel(const float* __restrict__ ot, const bf16* __restrict__ sw,
                               bf16* __restrict__ outx) {
  int pp = blockIdx.x;          // b*N + n
  int b = pp >> 14;
  int t = threadIdx.x;          // 256
  __shared__ float swl[NHEADS * GG];
  swl[t] = b2f(sw[(size_t)pp * 512 + t]);
  swl[t + 256] = b2f(sw[(size_t)pp * 512 + t + 256]);
  __syncthreads();
  int hh = t >> 5, d = t & 31;
  const float* otp = ot + ((size_t)(b * NHEADS + hh) * GG) * DHD + d;
  const float* swh = &swl[hh * GG];
  float a = 0.f;
#pragma unroll 8
  for (int g = 0; g < GG; ++g) a += otp[(size_t)g * DHD] * swh[g];
  outx[(size_t)pp * INNERC + t] = f2b(a);
}

// ---------- final LN3 + head (C -> 4) ----------
__global__ void head_kernel(const float* __restrict__ fx, const float* __restrict__ w,
                            const float* __restrict__ b, const float* __restrict__ wout,
                            const float* __restrict__ bout, float* __restrict__ out) {
  int pp = blockIdx.x;
  int t = threadIdx.x;
  float v = fx[(size_t)pp * CC + t];
  float s = wave_sum(v);
  float sq = wave_sum(v * v);
  __shared__ float ls[4], lq[4];
  int wid = t >> 6, lane = t & 63;
  if (lane == 0) { ls[wid] = s; lq[wid] = sq; }
  __syncthreads();
  float tot = ls[0] + ls[1] + ls[2] + ls[3];
  float totq = lq[0] + lq[1] + lq[2] + lq[3];
  float mean = tot * (1.0f / CC);
  float var = totq * (1.0f / CC) - mean * mean;
  float rstd = rsqrtf(var + 1e-5f);
  float xn = (v - mean) * rstd * w[t] + b[t];
  __shared__ float xs[CC];
  xs[t] = xn;
  __syncthreads();
  if (t < 4) {
    float a = bout[t];
    for (int c = 0; c < CC; ++c) a += xs[c] * wout[c * 4 + t];
    out[(size_t)pp * 4 + t] = a;
  }
}

extern "C" void kernel_launch(void* const* d_in, const int* in_sizes, int n_in,
                              void* d_out, int out_size, void* d_ws, size_t ws_size,
                              hipStream_t stream) {
  const float* fx_in      = (const float*)d_in[0];
  const float* ln1_w      = (const float*)d_in[1];
  const float* ln1_b      = (const float*)d_in[2];
  const float* convx_w    = (const float*)d_in[3];
  const float* convx_b    = (const float*)d_in[4];
  const float* convfx_w   = (const float*)d_in[5];
  const float* convfx_b   = (const float*)d_in[6];
  const float* slice_w    = (const float*)d_in[7];
  const float* slice_b    = (const float*)d_in[8];
  const float* temperature= (const float*)d_in[9];
  const float* wq         = (const float*)d_in[10];
  const float* wk         = (const float*)d_in[11];
  const float* wv         = (const float*)d_in[12];
  const float* wo         = (const float*)d_in[13];
  const float* bo         = (const float*)d_in[14];
  const float* ln2_w      = (const float*)d_in[15];
  const float* ln2_b      = (const float*)d_in[16];
  const float* w1         = (const float*)d_in[17];
  const float* b1         = (const float*)d_in[18];
  const float* w2         = (const float*)d_in[19];
  const float* b2         = (const float*)d_in[20];
  const float* ln3_w      = (const float*)d_in[21];
  const float* ln3_b      = (const float*)d_in[22];
  const float* w_out      = (const float*)d_in[23];
  const float* b_out      = (const float*)d_in[24];
  float* out = (float*)d_out;

  char* ws = (char*)d_ws;
  size_t off = 0;
  auto alloc = [&](size_t bytes) -> void* {
    void* p = ws + off;
    off += (bytes + 255) & ~(size_t)255;
    return p;
  };
  float* fx32  = (float*)alloc((size_t)BB * NN * CC * 4);    // 64 MiB
  bf16* xln    = (bf16*)alloc((size_t)BB * NN * CC * 2);     // 32 MiB
  char* uni    = (char*)alloc((size_t)BB * NN * HIDD * 2);   // 128 MiB union region
  bf16* xmid   = (bf16*)uni;                                  // 32 MiB
  bf16* fxmid  = (bf16*)(uni + (size_t)BB * NN * INNERC * 2); // 32 MiB
  bf16* swb    = (bf16*)(uni + (size_t)2 * BB * NN * INNERC * 2); // 64 MiB
  bf16* hidden = (bf16*)uni;                                  // aliases all three (dead by MLP)
  bf16* outx   = (bf16*)uni;                                  // aliases xmid (dead by deslice)
  // stp/normp alias the xmid region (xmid dead after slice_softmax; overwritten later by outx
  // only AFTER attn has consumed stp/normp)
  float* stp   = (float*)uni;                                        // 8 MiB
  float* normp = (float*)(uni + (size_t)SPLIT * BB * NHEADS * GG * DHD * 4);  // 256 KiB
  bf16* wtx    = (bf16*)alloc((size_t)LL * 9 * CC * INNERC * 2);
  bf16* wtfx   = (bf16*)alloc((size_t)LL * 9 * CC * INNERC * 2);
  bf16* w1t    = (bf16*)alloc((size_t)LL * CC * HIDD * 2);
  bf16* w2t    = (bf16*)alloc((size_t)LL * HIDD * CC * 2);
  bf16* wot    = (bf16*)alloc((size_t)LL * INNERC * CC * 2);
  float* otb   = (float*)alloc((size_t)BB * NHEADS * GG * DHD * 4);
  (void)ws_size; (void)in_sizes; (void)n_in; (void)out_size;

  // ---- weight prep: transpose + bf16 cast ----
  transpose_cast_kernel<<<dim3(8, 8, LL * 9), 256, 0, stream>>>(convx_w, wtx, CC, INNERC);
  transpose_cast_kernel<<<dim3(8, 8, LL * 9), 256, 0, stream>>>(convfx_w, wtfx, CC, INNERC);
  transpose_cast_kernel<<<dim3(32, 8, LL), 256, 0, stream>>>(w1, w1t, CC, HIDD);
  transpose_cast_kernel<<<dim3(8, 32, LL), 256, 0, stream>>>(w2, w2t, HIDD, CC);
  transpose_cast_kernel<<<dim3(8, 8, LL), 256, 0, stream>>>(wo, wot, INNERC, CC);

  hipMemcpyAsync(fx32, fx_in, (size_t)BB * NN * CC * sizeof(float),
                 hipMemcpyDeviceToDevice, stream);

  const int M = BB * NN;  // 65536
  for (int i = 0; i < LL; ++i) {
    ln_kernel<<<M, 256, 0, stream>>>(fx32, ln1_w + i * CC, ln1_b + i * CC, xln);
    conv_mfma_kernel<<<BB * HH * 2, 256, 0, stream>>>(
        xln, wtfx + (size_t)i * 9 * CC * INNERC, convfx_b + i * INNERC, fxmid);
    conv_mfma_kernel<<<BB * HH * 2, 256, 0, stream>>>(
        xln, wtx + (size_t)i * 9 * CC * INNERC, convx_b + i * INNERC, xmid);
    slice_softmax_kernel<<<M, 512, 0, stream>>>(
        xmid, slice_w + i * DHD * GG, slice_b + i * GG, temperature + i * NHEADS, swb);
    slice_st_kernel<<<dim3(SPLIT, NHEADS, BB), 256, 0, stream>>>(fxmid, swb, stp, normp);
    attn_kernel<<<BB * NHEADS, 64, 0, stream>>>(
        stp, normp, wq + i * DHD * DHD, wk + i * DHD * DHD, wv + i * DHD * DHD, otb);
    deslice_kernel<<<M, 256, 0, stream>>>(otb, swb, outx);
    gemm_kernel<1><<<dim3(M / 128, CC / 128), 256, 0, stream>>>(
        outx, wot + (size_t)i * INNERC * CC, bo + i * CC, nullptr, fx32, M, CC, INNERC);
    ln_kernel<<<M, 256, 0, stream>>>(fx32, ln2_w + i * CC, ln2_b + i * CC, xln);
    gemm_kernel<0><<<dim3(M / 128, HIDD / 128), 256, 0, stream>>>(
        xln, w1t + (size_t)i * CC * HIDD, b1 + i * HIDD, hidden, nullptr, M, HIDD, CC);
    gemm_kernel<1><<<dim3(M / 128, CC / 128), 256, 0, stream>>>(
        hidden, w2t + (size_t)i * HIDD * CC, b2 + i * CC, nullptr, fx32, M, CC, HIDD);
  }
  head_kernel<<<M, 256, 0, stream>>>(fx32, ln3_w, ln3_b, w_out, b_out, out);
}

// Round 5
// 3524.968 us; speedup vs baseline: 6.5884x; 1.2487x over previous
//
#include <hip/hip_runtime.h>
#include <hip/hip_bf16.h>

typedef __hip_bfloat16 bf16;
typedef __bf16 bfv8 __attribute__((ext_vector_type(8)));
typedef float f32x4 __attribute__((ext_vector_type(4)));

#define BB 4
#define HH 128
#define WWI 128
#define NN 16384      // HH*WWI
#define CC 256
#define LL 4
#define NHEADS 8
#define DHD 32
#define GG 64
#define INNERC 256    // NHEADS*DHD
#define HIDD 1024
#define SPLIT 32      // split-K blocks per (b,h) in slice_st
#define SSP 16        // points per block in slice_softmax

__device__ __forceinline__ float b2f(bf16 x) { return __bfloat162float(x); }
__device__ __forceinline__ bf16 f2b(float x) { return __float2bfloat16(x); }
__device__ __forceinline__ float us2f(unsigned short v) {
  return __uint_as_float(((unsigned)v) << 16);
}

__device__ __forceinline__ float wave_sum(float v) {
#pragma unroll
  for (int off = 32; off > 0; off >>= 1) v += __shfl_down(v, off, 64);
  return v;
}

__device__ __forceinline__ float gelu_exact(float x) {
  return 0.5f * x * (1.0f + erff(x * 0.70710678118654752f));
}

// ---------- batched transpose+cast: src fp32 [T][R][Cm] -> dst bf16 [T][Cm][R] ----------
__global__ void transpose_cast_kernel(const float* __restrict__ src, bf16* __restrict__ dst,
                                      int R, int Cm) {
  __shared__ float tile[32][33];
  int tb = blockIdx.z;
  const float* s = src + (size_t)tb * R * Cm;
  bf16* d = dst + (size_t)tb * R * Cm;
  int c0 = blockIdx.x * 32, r0 = blockIdx.y * 32;
  int tx = threadIdx.x & 31, ty = threadIdx.x >> 5;  // 32 x 8
  for (int rr = ty; rr < 32; rr += 8) {
    int r = r0 + rr, c = c0 + tx;
    tile[rr][tx] = (r < R && c < Cm) ? s[(size_t)r * Cm + c] : 0.f;
  }
  __syncthreads();
  for (int cc = ty; cc < 32; cc += 8) {
    int c = c0 + cc, r = r0 + tx;
    if (c < Cm && r < R) d[(size_t)c * R + r] = f2b(tile[tx][cc]);
  }
}

// ---------- LayerNorm over C=256 per point; block = 256 threads ----------
__global__ void ln_kernel(const float* __restrict__ x, const float* __restrict__ w,
                          const float* __restrict__ b, bf16* __restrict__ out) {
  int pp = blockIdx.x;
  int t = threadIdx.x;
  float v = x[(size_t)pp * CC + t];
  float s = wave_sum(v);
  float sq = wave_sum(v * v);
  __shared__ float ls[4], lq[4];
  int wid = t >> 6, lane = t & 63;
  if (lane == 0) { ls[wid] = s; lq[wid] = sq; }
  __syncthreads();
  float tot = ls[0] + ls[1] + ls[2] + ls[3];
  float totq = lq[0] + lq[1] + lq[2] + lq[3];
  float mean = tot * (1.0f / CC);
  float var = totq * (1.0f / CC) - mean * mean;
  float rstd = rsqrtf(var + 1e-5f);
  float o = (v - mean) * rstd * w[t] + b[t];
  out[(size_t)pp * CC + t] = f2b(o);
}

// ---------- 3x3 conv as implicit MFMA GEMM ----------
__global__ __launch_bounds__(256, 2) void conv_mfma_kernel(
    const bf16* __restrict__ xln, const bf16* __restrict__ wt,
    const float* __restrict__ bias, bf16* __restrict__ out) {
  __shared__ __align__(16) unsigned short As[3 * 130 * 64];
  __shared__ __align__(16) unsigned short Bsm[128 * 64];
  int bid = blockIdx.x;
  int nh = bid & 1;
  int h = (bid >> 1) & 127;
  int b = bid >> 8;
  int t = threadIdx.x, lane = t & 63, wid = t >> 6;
  int wm = (wid >> 1) * 64, wn = (wid & 1) * 64;
  int l15 = lane & 15, l4 = lane >> 4;
  f32x4 acc[4][4];
#pragma unroll
  for (int mi = 0; mi < 4; ++mi)
#pragma unroll
    for (int ni = 0; ni < 4; ++ni) acc[mi][ni] = (f32x4){0.f, 0.f, 0.f, 0.f};
  const bf16* xbase = xln + (size_t)b * NN * CC;

  for (int q = 0; q < 4; ++q) {
    __syncthreads();
    for (int u = t; u < 3120; u += 256) {
      int jp = u & 7;
      int pc = u >> 3;
      int r = pc / 130, cl = pc - r * 130;
      int j = jp ^ (cl & 7);
      int gr = h + r - 1, gc = cl - 1;
      uint4 v = make_uint4(0u, 0u, 0u, 0u);
      if ((unsigned)gr < 128u && (unsigned)gc < 128u)
        v = *(const uint4*)(xbase + ((size_t)(gr * WWI + gc)) * CC + q * 64 + j * 8);
      *(uint4*)(&As[(size_t)u * 8]) = v;
    }
    for (int tap = 0; tap < 9; ++tap) {
      if (tap > 0) __syncthreads();
      {
        const bf16* wsrc = wt + ((size_t)tap * 256 + nh * 128) * 256 + q * 64;
#pragma unroll
        for (int i = 0; i < 4; ++i) {
          int u = t + (i << 8);
          int n = u >> 3, jp = u & 7, j = jp ^ (n & 7);
          uint4 v = *(const uint4*)(wsrc + (size_t)n * 256 + j * 8);
          *(uint4*)(&Bsm[(size_t)u * 8]) = v;
        }
      }
      __syncthreads();
      int ky = tap / 3, kx = tap - ky * 3;
#pragma unroll
      for (int s = 0; s < 2; ++s) {
        bfv8 af[4], bfr[4];
#pragma unroll
        for (int mi = 0; mi < 4; ++mi) {
          int cl = wm + mi * 16 + l15 + kx;
          af[mi] = *(const bfv8*)(&As[((size_t)(ky * 130 + cl)) * 64 +
                                      (((s * 4 + l4) ^ (cl & 7)) << 3)]);
        }
#pragma unroll
        for (int ni = 0; ni < 4; ++ni) {
          int rn = wn + ni * 16 + l15;
          bfr[ni] = *(const bfv8*)(&Bsm[(size_t)rn * 64 + (((s * 4 + l4) ^ (rn & 7)) << 3)]);
        }
#pragma unroll
        for (int mi = 0; mi < 4; ++mi)
#pragma unroll
          for (int ni = 0; ni < 4; ++ni)
            acc[mi][ni] = __builtin_amdgcn_mfma_f32_16x16x32_bf16(af[mi], bfr[ni], acc[mi][ni], 0, 0, 0);
      }
    }
  }
  int colB = wn + l15;
  int rowB = wm + l4 * 4;
#pragma unroll
  for (int ni = 0; ni < 4; ++ni) {
    int oc = nh * 128 + colB + ni * 16;
    float bv = bias[oc];
#pragma unroll
    for (int mi = 0; mi < 4; ++mi) {
#pragma unroll
      for (int r = 0; r < 4; ++r) {
        int pix = rowB + mi * 16 + r;
        out[((size_t)(b * NN + h * WWI + pix)) * CC + oc] = f2b(acc[mi][ni][r] + bv);
      }
    }
  }
}

// ---------- generic MFMA GEMM: A[M,K] bf16, BT[N,K] bf16 ----------
template <int MODE>
__global__ __launch_bounds__(256, 2) void gemm_kernel(
    const bf16* __restrict__ A, const bf16* __restrict__ BT,
    const float* __restrict__ bias, bf16* __restrict__ outb,
    float* __restrict__ outf, int M, int N, int K) {
  __shared__ __align__(16) unsigned short As[128 * 64];
  __shared__ __align__(16) unsigned short Bsm[128 * 64];
  int m0 = blockIdx.x * 128, n0 = blockIdx.y * 128;
  int t = threadIdx.x, lane = t & 63, wid = t >> 6;
  int wm = (wid >> 1) * 64, wn = (wid & 1) * 64;
  int l15 = lane & 15, l4 = lane >> 4;
  f32x4 acc[4][4];
#pragma unroll
  for (int mi = 0; mi < 4; ++mi)
#pragma unroll
    for (int ni = 0; ni < 4; ++ni) acc[mi][ni] = (f32x4){0.f, 0.f, 0.f, 0.f};

  for (int kb = 0; kb < K; kb += 64) {
    __syncthreads();
    uint4 va[4], vb[4];
#pragma unroll
    for (int i = 0; i < 4; ++i) {
      int u = t + (i << 8);
      int row = u >> 3, j = (u & 7) ^ (row & 7);
      va[i] = *(const uint4*)(A + (size_t)(m0 + row) * K + kb + j * 8);
      vb[i] = *(const uint4*)(BT + (size_t)(n0 + row) * K + kb + j * 8);
    }
#pragma unroll
    for (int i = 0; i < 4; ++i) {
      int u = t + (i << 8);
      *(uint4*)(&As[(size_t)u * 8]) = va[i];
      *(uint4*)(&Bsm[(size_t)u * 8]) = vb[i];
    }
    __syncthreads();
#pragma unroll
    for (int s = 0; s < 2; ++s) {
      bfv8 af[4], bfr[4];
#pragma unroll
      for (int mi = 0; mi < 4; ++mi) {
        int row = wm + mi * 16 + l15;
        af[mi] = *(const bfv8*)(&As[(size_t)row * 64 + (((s * 4 + l4) ^ (row & 7)) << 3)]);
      }
#pragma unroll
      for (int ni = 0; ni < 4; ++ni) {
        int rn = wn + ni * 16 + l15;
        bfr[ni] = *(const bfv8*)(&Bsm[(size_t)rn * 64 + (((s * 4 + l4) ^ (rn & 7)) << 3)]);
      }
#pragma unroll
      for (int mi = 0; mi < 4; ++mi)
#pragma unroll
        for (int ni = 0; ni < 4; ++ni)
          acc[mi][ni] = __builtin_amdgcn_mfma_f32_16x16x32_bf16(af[mi], bfr[ni], acc[mi][ni], 0, 0, 0);
    }
  }
  int colB = n0 + wn + l15;
  int rowB = m0 + wm + l4 * 4;
#pragma unroll
  for (int ni = 0; ni < 4; ++ni) {
    int col = colB + ni * 16;
    float bv = bias[col];
#pragma unroll
    for (int mi = 0; mi < 4; ++mi) {
#pragma unroll
      for (int r = 0; r < 4; ++r) {
        int row = rowB + mi * 16 + r;
        float v = acc[mi][ni][r] + bv;
        if (MODE == 0) outb[(size_t)row * N + col] = f2b(gelu_exact(v));
        else outf[(size_t)row * N + col] += v;
      }
    }
  }
}

// ---------- slice logits + softmax over G; 16 points/block, weights in LDS ----------
__global__ __launch_bounds__(256) void slice_softmax_kernel(
    const bf16* __restrict__ xmid, const float* __restrict__ sw_w,
    const float* __restrict__ sw_b, const float* __restrict__ temp,
    bf16* __restrict__ swout) {
  __shared__ float wsm[32][64];     // 8 KiB  [d][g]
  __shared__ float xm[SSP][256];    // 16 KiB
  __shared__ float bias_s[64];
  __shared__ float rtc[8];
  int p0 = blockIdx.x * SSP;
  int t = threadIdx.x;
  for (int i = t; i < 2048; i += 256) wsm[i >> 6][i & 63] = sw_w[i];
  if (t < 64) bias_s[t] = sw_b[t];
  if (t < 8) {
    float x = temp[t];
    rtc[t] = 1.0f / fminf(fmaxf(x, 0.1f), 5.0f);
  }
  const unsigned short* xg = (const unsigned short*)xmid + (size_t)p0 * 256;
#pragma unroll
  for (int i2 = t; i2 < SSP * 32; i2 += 256) {   // 512 groups of 8 bf16
    uint4 v = ((const uint4*)xg)[i2];
    int p = i2 >> 5, c = (i2 & 31) << 3;
    xm[p][c + 0] = us2f((unsigned short)(v.x & 0xffff));
    xm[p][c + 1] = us2f((unsigned short)(v.x >> 16));
    xm[p][c + 2] = us2f((unsigned short)(v.y & 0xffff));
    xm[p][c + 3] = us2f((unsigned short)(v.y >> 16));
    xm[p][c + 4] = us2f((unsigned short)(v.z & 0xffff));
    xm[p][c + 5] = us2f((unsigned short)(v.z >> 16));
    xm[p][c + 6] = us2f((unsigned short)(v.w & 0xffff));
    xm[p][c + 7] = us2f((unsigned short)(v.w >> 16));
  }
  __syncthreads();
  int g = t & 63, pq = t >> 6;
  for (int pp2 = 0; pp2 < SSP / 4; ++pp2) {
    int p = pp2 * 4 + pq;
#pragma unroll
    for (int h = 0; h < NHEADS; ++h) {
      float acc = bias_s[g];
      const float* xr = &xm[p][h * 32];
#pragma unroll
      for (int d = 0; d < 32; ++d) acc += xr[d] * wsm[d][g];
      float logit = acc * rtc[h];
      float m = logit;
#pragma unroll
      for (int off = 32; off > 0; off >>= 1) m = fmaxf(m, __shfl_xor(m, off, 64));
      float e = __expf(logit - m);
      float s = e;
#pragma unroll
      for (int off = 32; off > 0; off >>= 1) s += __shfl_xor(s, off, 64);
      swout[(size_t)(p0 + p) * 512 + h * 64 + g] = f2b(e / s);
    }
  }
}

// ---------- slice reduce as split-K MFMA outer product ----------
__global__ __launch_bounds__(256) void slice_st_kernel(
    const bf16* __restrict__ fxmid, const bf16* __restrict__ sw,
    float* __restrict__ stp, float* __restrict__ normp) {
  __shared__ __align__(16) unsigned short sw_s[64 * 64];
  __shared__ __align__(16) unsigned short fx_s[32 * 64];
  __shared__ float npart[2][64];
  int split = blockIdx.x, h = blockIdx.y, b = blockIdx.z;
  int t = threadIdx.x, w = t >> 6, lane = t & 63;
  int l15 = lane & 15, q4 = lane >> 4;
  int ns0 = split * (NN / SPLIT);
  const int NT = (NN / SPLIT) / 64;
  f32x4 acc0 = {0.f, 0.f, 0.f, 0.f}, acc1 = {0.f, 0.f, 0.f, 0.f};
  float nacc = 0.f;
  const unsigned short* swg = (const unsigned short*)sw + (size_t)b * NN * 512 + h * 64;
  const unsigned short* fxg = (const unsigned short*)fxmid + (size_t)b * NN * 256 + h * 32;

  for (int kt = 0; kt < NT; ++kt) {
    int n0 = ns0 + kt * 64;
    __syncthreads();
    if (w < 2) {
      int g = lane;
#pragma unroll
      for (int i = 0; i < 4; ++i) {
        int j = w + 2 * i;
        const unsigned short* p = swg + (size_t)(n0 + j * 8) * 512 + g;
        unsigned short v0 = p[0],     v1 = p[512],  v2 = p[1024], v3 = p[1536];
        unsigned short v4 = p[2048],  v5 = p[2560], v6 = p[3072], v7 = p[3584];
        nacc += us2f(v0) + us2f(v1) + us2f(v2) + us2f(v3) +
                us2f(v4) + us2f(v5) + us2f(v6) + us2f(v7);
        uint4 pk = make_uint4((unsigned)v0 | ((unsigned)v1 << 16),
                              (unsigned)v2 | ((unsigned)v3 << 16),
                              (unsigned)v4 | ((unsigned)v5 << 16),
                              (unsigned)v6 | ((unsigned)v7 << 16));
        ((uint4*)sw_s)[g * 8 + (j ^ (g & 7))] = pk;
      }
    } else {
      int d = lane & 31, nh = lane >> 5, w3 = w - 2;
#pragma unroll
      for (int i = 0; i < 2; ++i) {
        int nbase = (w3 * 2 + i) * 16 + nh * 8;
        const unsigned short* p = fxg + (size_t)(n0 + nbase) * 256 + d;
        unsigned short v0 = p[0],    v1 = p[256],  v2 = p[512],  v3 = p[768];
        unsigned short v4 = p[1024], v5 = p[1280], v6 = p[1536], v7 = p[1792];
        uint4 pk = make_uint4((unsigned)v0 | ((unsigned)v1 << 16),
                              (unsigned)v2 | ((unsigned)v3 << 16),
                              (unsigned)v4 | ((unsigned)v5 << 16),
                              (unsigned)v6 | ((unsigned)v7 << 16));
        int u = nbase >> 3;
        ((uint4*)fx_s)[d * 8 + (u ^ (d & 7))] = pk;
      }
    }
    __syncthreads();
    int gg = w * 16 + l15;
    int d0 = l15, d1 = 16 + l15;
#pragma unroll
    for (int ks = 0; ks < 2; ++ks) {
      bfv8 af  = ((const bfv8*)sw_s)[gg * 8 + ((ks * 4 + q4) ^ (gg & 7))];
      bfv8 bf0 = ((const bfv8*)fx_s)[d0 * 8 + ((ks * 4 + q4) ^ (d0 & 7))];
      bfv8 bf1 = ((const bfv8*)fx_s)[d1 * 8 + ((ks * 4 + q4) ^ (d1 & 7))];
      acc0 = __builtin_amdgcn_mfma_f32_16x16x32_bf16(af, bf0, acc0, 0, 0, 0);
      acc1 = __builtin_amdgcn_mfma_f32_16x16x32_bf16(af, bf1, acc1, 0, 0, 0);
    }
  }
  if (w < 2) npart[w][lane] = nacc;
  __syncthreads();
  int bh = b * NHEADS + h;
  if (t < 64) normp[(size_t)split * (BB * NHEADS * GG) + bh * 64 + t] = npart[0][t] + npart[1][t];
  size_t base = ((size_t)split * (BB * NHEADS * GG) + bh * 64) * 32;
#pragma unroll
  for (int r = 0; r < 4; ++r) {
    int g = w * 16 + q4 * 4 + r;
    stp[base + (size_t)g * 32 + l15] = acc0[r];
    stp[base + (size_t)g * 32 + 16 + l15] = acc1[r];
  }
}

// ---------- attention over G=64 per (b,h); 256 threads; weights + reduction in LDS ----------
__global__ __launch_bounds__(256) void attn_kernel(
    const float* __restrict__ stp, const float* __restrict__ normp,
    const float* __restrict__ wq, const float* __restrict__ wk,
    const float* __restrict__ wv, float* __restrict__ ot) {
  __shared__ float wqs[32 * 32], wks[32 * 32], wvs[32 * 32];  // 12 KiB
  __shared__ float st[GG][DHD + 1];                           // 8.25 KiB
  __shared__ float qq[GG][DHD + 1], kk[GG][DHD + 1], vv[GG][DHD + 1];
  __shared__ float pm[GG][GG + 1];                            // 16.25 KiB
  __shared__ float nrm[GG];
  int bh = blockIdx.x;
  int t = threadIdx.x;
  ((float4*)wqs)[t] = ((const float4*)wq)[t];
  ((float4*)wks)[t] = ((const float4*)wk)[t];
  ((float4*)wvs)[t] = ((const float4*)wv)[t];
  if (t < 64) {
    float ns = 0.f;
    for (int s = 0; s < SPLIT; ++s) ns += normp[(size_t)s * (BB * NHEADS * GG) + bh * 64 + t];
    nrm[t] = 1.0f / (ns + 1e-5f);
  }
  __syncthreads();
#pragma unroll
  for (int i = 0; i < 8; ++i) {
    int idx = t + i * 256;
    int g = idx >> 5, d = idx & 31;
    float a = 0.f;
    for (int s = 0; s < SPLIT; ++s)
      a += stp[((size_t)s * (BB * NHEADS * GG) + bh * 64 + g) * 32 + d];
    st[g][d] = a * nrm[g];
  }
  __syncthreads();
#pragma unroll
  for (int i = 0; i < 8; ++i) {
    int idx = t + i * 256;
    int g = idx >> 5, d = idx & 31;
    float aq = 0.f, ak = 0.f, av = 0.f;
#pragma unroll
    for (int c = 0; c < 32; ++c) {
      float sv = st[g][c];
      aq += sv * wqs[c * 32 + d];
      ak += sv * wks[c * 32 + d];
      av += sv * wvs[c * 32 + d];
    }
    qq[g][d] = aq; kk[g][d] = ak; vv[g][d] = av;
  }
  __syncthreads();
  {
    int g = t >> 2, sub = t & 3;
    float sc[16];
    float m = -1e30f;
    const float scale = 0.17677669529663687f;
#pragma unroll
    for (int jj = 0; jj < 16; ++jj) {
      int j = sub * 16 + jj;
      float a = 0.f;
#pragma unroll
      for (int d = 0; d < 32; ++d) a += qq[g][d] * kk[j][d];
      a *= scale;
      sc[jj] = a;
      m = fmaxf(m, a);
    }
    m = fmaxf(m, __shfl_xor(m, 1, 64));
    m = fmaxf(m, __shfl_xor(m, 2, 64));
    float ssum = 0.f;
#pragma unroll
    for (int jj = 0; jj < 16; ++jj) { sc[jj] = __expf(sc[jj] - m); ssum += sc[jj]; }
    ssum += __shfl_xor(ssum, 1, 64);
    ssum += __shfl_xor(ssum, 2, 64);
    float rs = 1.0f / ssum;
#pragma unroll
    for (int jj = 0; jj < 16; ++jj) pm[g][sub * 16 + jj] = sc[jj] * rs;
  }
  __syncthreads();
#pragma unroll
  for (int i = 0; i < 8; ++i) {
    int idx = t + i * 256;
    int g = idx >> 5, d = idx & 31;
    float a = 0.f;
#pragma unroll
    for (int j = 0; j < GG; ++j) a += pm[g][j] * vv[j][d];
    ot[((size_t)bh * GG + g) * DHD + d] = a;
  }
}

// ---------- deslice: out_x[p, h*32+d] = sum_g ot[b,h,g,d]*sw[p,h*64+g] ----------
__global__ void deslice_kernel(const float* __restrict__ ot, const bf16* __restrict__ sw,
                               bf16* __restrict__ outx) {
  int pp = blockIdx.x;
  int b = pp >> 14;
  int t = threadIdx.x;
  __shared__ float swl[NHEADS * GG];
  swl[t] = b2f(sw[(size_t)pp * 512 + t]);
  swl[t + 256] = b2f(sw[(size_t)pp * 512 + t + 256]);
  __syncthreads();
  int hh = t >> 5, d = t & 31;
  const float* otp = ot + ((size_t)(b * NHEADS + hh) * GG) * DHD + d;
  const float* swh = &swl[hh * GG];
  float a = 0.f;
#pragma unroll 8
  for (int g = 0; g < GG; ++g) a += otp[(size_t)g * DHD] * swh[g];
  outx[(size_t)pp * INNERC + t] = f2b(a);
}

// ---------- final LN3 + head (C -> 4) ----------
__global__ void head_kernel(const float* __restrict__ fx, const float* __restrict__ w,
                            const float* __restrict__ b, const float* __restrict__ wout,
                            const float* __restrict__ bout, float* __restrict__ out) {
  int pp = blockIdx.x;
  int t = threadIdx.x;
  float v = fx[(size_t)pp * CC + t];
  float s = wave_sum(v);
  float sq = wave_sum(v * v);
  __shared__ float ls[4], lq[4];
  int wid = t >> 6, lane = t & 63;
  if (lane == 0) { ls[wid] = s; lq[wid] = sq; }
  __syncthreads();
  float tot = ls[0] + ls[1] + ls[2] + ls[3];
  float totq = lq[0] + lq[1] + lq[2] + lq[3];
  float mean = tot * (1.0f / CC);
  float var = totq * (1.0f / CC) - mean * mean;
  float rstd = rsqrtf(var + 1e-5f);
  float xn = (v - mean) * rstd * w[t] + b[t];
  __shared__ float xs[CC];
  xs[t] = xn;
  __syncthreads();
  if (t < 4) {
    float a = bout[t];
    for (int c = 0; c < CC; ++c) a += xs[c] * wout[c * 4 + t];
    out[(size_t)pp * 4 + t] = a;
  }
}

extern "C" void kernel_launch(void* const* d_in, const int* in_sizes, int n_in,
                              void* d_out, int out_size, void* d_ws, size_t ws_size,
                              hipStream_t stream) {
  const float* fx_in      = (const float*)d_in[0];
  const float* ln1_w      = (const float*)d_in[1];
  const float* ln1_b      = (const float*)d_in[2];
  const float* convx_w    = (const float*)d_in[3];
  const float* convx_b    = (const float*)d_in[4];
  const float* convfx_w   = (const float*)d_in[5];
  const float* convfx_b   = (const float*)d_in[6];
  const float* slice_w    = (const float*)d_in[7];
  const float* slice_b    = (const float*)d_in[8];
  const float* temperature= (const float*)d_in[9];
  const float* wq         = (const float*)d_in[10];
  const float* wk         = (const float*)d_in[11];
  const float* wv         = (const float*)d_in[12];
  const float* wo         = (const float*)d_in[13];
  const float* bo         = (const float*)d_in[14];
  const float* ln2_w      = (const float*)d_in[15];
  const float* ln2_b      = (const float*)d_in[16];
  const float* w1         = (const float*)d_in[17];
  const float* b1         = (const float*)d_in[18];
  const float* w2         = (const float*)d_in[19];
  const float* b2         = (const float*)d_in[20];
  const float* ln3_w      = (const float*)d_in[21];
  const float* ln3_b      = (const float*)d_in[22];
  const float* w_out      = (const float*)d_in[23];
  const float* b_out      = (const float*)d_in[24];
  float* out = (float*)d_out;

  char* ws = (char*)d_ws;
  size_t off = 0;
  auto alloc = [&](size_t bytes) -> void* {
    void* p = ws + off;
    off += (bytes + 255) & ~(size_t)255;
    return p;
  };
  float* fx32  = (float*)alloc((size_t)BB * NN * CC * 4);    // 64 MiB
  bf16* xln    = (bf16*)alloc((size_t)BB * NN * CC * 2);     // 32 MiB
  char* uni    = (char*)alloc((size_t)BB * NN * HIDD * 2);   // 128 MiB union region
  bf16* xmid   = (bf16*)uni;
  bf16* fxmid  = (bf16*)(uni + (size_t)BB * NN * INNERC * 2);
  bf16* swb    = (bf16*)(uni + (size_t)2 * BB * NN * INNERC * 2);
  bf16* hidden = (bf16*)uni;
  bf16* outx   = (bf16*)uni;
  float* stp   = (float*)uni;                                        // 8 MiB (aliases dead xmid)
  float* normp = (float*)(uni + (size_t)SPLIT * BB * NHEADS * GG * DHD * 4);
  bf16* wtx    = (bf16*)alloc((size_t)LL * 9 * CC * INNERC * 2);
  bf16* wtfx   = (bf16*)alloc((size_t)LL * 9 * CC * INNERC * 2);
  bf16* w1t    = (bf16*)alloc((size_t)LL * CC * HIDD * 2);
  bf16* w2t    = (bf16*)alloc((size_t)LL * HIDD * CC * 2);
  bf16* wot    = (bf16*)alloc((size_t)LL * INNERC * CC * 2);
  float* otb   = (float*)alloc((size_t)BB * NHEADS * GG * DHD * 4);
  (void)ws_size; (void)in_sizes; (void)n_in; (void)out_size;

  transpose_cast_kernel<<<dim3(8, 8, LL * 9), 256, 0, stream>>>(convx_w, wtx, CC, INNERC);
  transpose_cast_kernel<<<dim3(8, 8, LL * 9), 256, 0, stream>>>(convfx_w, wtfx, CC, INNERC);
  transpose_cast_kernel<<<dim3(32, 8, LL), 256, 0, stream>>>(w1, w1t, CC, HIDD);
  transpose_cast_kernel<<<dim3(8, 32, LL), 256, 0, stream>>>(w2, w2t, HIDD, CC);
  transpose_cast_kernel<<<dim3(8, 8, LL), 256, 0, stream>>>(wo, wot, INNERC, CC);

  hipMemcpyAsync(fx32, fx_in, (size_t)BB * NN * CC * sizeof(float),
                 hipMemcpyDeviceToDevice, stream);

  const int M = BB * NN;  // 65536
  for (int i = 0; i < LL; ++i) {
    ln_kernel<<<M, 256, 0, stream>>>(fx32, ln1_w + i * CC, ln1_b + i * CC, xln);
    conv_mfma_kernel<<<BB * HH * 2, 256, 0, stream>>>(
        xln, wtfx + (size_t)i * 9 * CC * INNERC, convfx_b + i * INNERC, fxmid);
    conv_mfma_kernel<<<BB * HH * 2, 256, 0, stream>>>(
        xln, wtx + (size_t)i * 9 * CC * INNERC, convx_b + i * INNERC, xmid);
    slice_softmax_kernel<<<M / SSP, 256, 0, stream>>>(
        xmid, slice_w + i * DHD * GG, slice_b + i * GG, temperature + i * NHEADS, swb);
    slice_st_kernel<<<dim3(SPLIT, NHEADS, BB), 256, 0, stream>>>(fxmid, swb, stp, normp);
    attn_kernel<<<BB * NHEADS, 256, 0, stream>>>(
        stp, normp, wq + i * DHD * DHD, wk + i * DHD * DHD, wv + i * DHD * DHD, otb);
    deslice_kernel<<<M, 256, 0, stream>>>(otb, swb, outx);
    gemm_kernel<1><<<dim3(M / 128, CC / 128), 256, 0, stream>>>(
        outx, wot + (size_t)i * INNERC * CC, bo + i * CC, nullptr, fx32, M, CC, INNERC);
    ln_kernel<<<M, 256, 0, stream>>>(fx32, ln2_w + i * CC, ln2_b + i * CC, xln);
    gemm_kernel<0><<<dim3(M / 128, HIDD / 128), 256, 0, stream>>>(
        xln, w1t + (size_t)i * CC * HIDD, b1 + i * HIDD, hidden, nullptr, M, HIDD, CC);
    gemm_kernel<1><<<dim3(M / 128, CC / 128), 256, 0, stream>>>(
        hidden, w2t + (size_t)i * HIDD * CC, b2 + i * CC, nullptr, fx32, M, CC, HIDD);
  }
  head_kernel<<<M, 256, 0, stream>>>(fx32, ln3_w, ln3_b, w_out, b_out, out);
}

// Round 6
// 3189.284 us; speedup vs baseline: 7.2818x; 1.1053x over previous
//
#include <hip/hip_runtime.h>
#include <hip/hip_bf16.h>

typedef __hip_bfloat16 bf16;
typedef __bf16 bfv8 __attribute__((ext_vector_type(8)));
typedef float f32x4 __attribute__((ext_vector_type(4)));

#define BB 4
#define HH 128
#define WWI 128
#define NN 16384      // HH*WWI
#define CC 256
#define LL 4
#define NHEADS 8
#define DHD 32
#define GG 64
#define INNERC 256    // NHEADS*DHD
#define HIDD 1024
#define SPLIT 32      // split-K blocks per (b,h) in slice_st
#define SSP 16        // points per block in slice_softmax

__device__ __forceinline__ float b2f(bf16 x) { return __bfloat162float(x); }
__device__ __forceinline__ bf16 f2b(float x) { return __float2bfloat16(x); }
__device__ __forceinline__ float us2f(unsigned short v) {
  return __uint_as_float(((unsigned)v) << 16);
}

__device__ __forceinline__ float wave_sum(float v) {
#pragma unroll
  for (int off = 32; off > 0; off >>= 1) v += __shfl_down(v, off, 64);
  return v;
}

__device__ __forceinline__ float gelu_exact(float x) {
  return 0.5f * x * (1.0f + erff(x * 0.70710678118654752f));
}

// ---------- batched transpose+cast: src fp32 [T][R][Cm] -> dst bf16 [T][Cm][R] ----------
__global__ void transpose_cast_kernel(const float* __restrict__ src, bf16* __restrict__ dst,
                                      int R, int Cm) {
  __shared__ float tile[32][33];
  int tb = blockIdx.z;
  const float* s = src + (size_t)tb * R * Cm;
  bf16* d = dst + (size_t)tb * R * Cm;
  int c0 = blockIdx.x * 32, r0 = blockIdx.y * 32;
  int tx = threadIdx.x & 31, ty = threadIdx.x >> 5;  // 32 x 8
  for (int rr = ty; rr < 32; rr += 8) {
    int r = r0 + rr, c = c0 + tx;
    tile[rr][tx] = (r < R && c < Cm) ? s[(size_t)r * Cm + c] : 0.f;
  }
  __syncthreads();
  for (int cc = ty; cc < 32; cc += 8) {
    int c = c0 + cc, r = r0 + tx;
    if (c < Cm && r < R) d[(size_t)c * R + r] = f2b(tile[tx][cc]);
  }
}

// ---------- LayerNorm over C=256 per point; block = 256 threads ----------
__global__ void ln_kernel(const float* __restrict__ x, const float* __restrict__ w,
                          const float* __restrict__ b, bf16* __restrict__ out) {
  int pp = blockIdx.x;
  int t = threadIdx.x;
  float v = x[(size_t)pp * CC + t];
  float s = wave_sum(v);
  float sq = wave_sum(v * v);
  __shared__ float ls[4], lq[4];
  int wid = t >> 6, lane = t & 63;
  if (lane == 0) { ls[wid] = s; lq[wid] = sq; }
  __syncthreads();
  float tot = ls[0] + ls[1] + ls[2] + ls[3];
  float totq = lq[0] + lq[1] + lq[2] + lq[3];
  float mean = tot * (1.0f / CC);
  float var = totq * (1.0f / CC) - mean * mean;
  float rstd = rsqrtf(var + 1e-5f);
  float o = (v - mean) * rstd * w[t] + b[t];
  out[(size_t)pp * CC + t] = f2b(o);
}

// ---------- 3x3 conv as implicit MFMA GEMM ----------
__global__ __launch_bounds__(256, 2) void conv_mfma_kernel(
    const bf16* __restrict__ xln, const bf16* __restrict__ wt,
    const float* __restrict__ bias, bf16* __restrict__ out) {
  __shared__ __align__(16) unsigned short As[3 * 130 * 64];
  __shared__ __align__(16) unsigned short Bsm[128 * 64];
  int bid = blockIdx.x;
  int nh = bid & 1;
  int h = (bid >> 1) & 127;
  int b = bid >> 8;
  int t = threadIdx.x, lane = t & 63, wid = t >> 6;
  int wm = (wid >> 1) * 64, wn = (wid & 1) * 64;
  int l15 = lane & 15, l4 = lane >> 4;
  f32x4 acc[4][4];
#pragma unroll
  for (int mi = 0; mi < 4; ++mi)
#pragma unroll
    for (int ni = 0; ni < 4; ++ni) acc[mi][ni] = (f32x4){0.f, 0.f, 0.f, 0.f};
  const bf16* xbase = xln + (size_t)b * NN * CC;

  for (int q = 0; q < 4; ++q) {
    __syncthreads();
    for (int u = t; u < 3120; u += 256) {
      int jp = u & 7;
      int pc = u >> 3;
      int r = pc / 130, cl = pc - r * 130;
      int j = jp ^ (cl & 7);
      int gr = h + r - 1, gc = cl - 1;
      uint4 v = make_uint4(0u, 0u, 0u, 0u);
      if ((unsigned)gr < 128u && (unsigned)gc < 128u)
        v = *(const uint4*)(xbase + ((size_t)(gr * WWI + gc)) * CC + q * 64 + j * 8);
      *(uint4*)(&As[(size_t)u * 8]) = v;
    }
    for (int tap = 0; tap < 9; ++tap) {
      if (tap > 0) __syncthreads();
      {
        const bf16* wsrc = wt + ((size_t)tap * 256 + nh * 128) * 256 + q * 64;
#pragma unroll
        for (int i = 0; i < 4; ++i) {
          int u = t + (i << 8);
          int n = u >> 3, jp = u & 7, j = jp ^ (n & 7);
          uint4 v = *(const uint4*)(wsrc + (size_t)n * 256 + j * 8);
          *(uint4*)(&Bsm[(size_t)u * 8]) = v;
        }
      }
      __syncthreads();
      int ky = tap / 3, kx = tap - ky * 3;
#pragma unroll
      for (int s = 0; s < 2; ++s) {
        bfv8 af[4], bfr[4];
#pragma unroll
        for (int mi = 0; mi < 4; ++mi) {
          int cl = wm + mi * 16 + l15 + kx;
          af[mi] = *(const bfv8*)(&As[((size_t)(ky * 130 + cl)) * 64 +
                                      (((s * 4 + l4) ^ (cl & 7)) << 3)]);
        }
#pragma unroll
        for (int ni = 0; ni < 4; ++ni) {
          int rn = wn + ni * 16 + l15;
          bfr[ni] = *(const bfv8*)(&Bsm[(size_t)rn * 64 + (((s * 4 + l4) ^ (rn & 7)) << 3)]);
        }
#pragma unroll
        for (int mi = 0; mi < 4; ++mi)
#pragma unroll
          for (int ni = 0; ni < 4; ++ni)
            acc[mi][ni] = __builtin_amdgcn_mfma_f32_16x16x32_bf16(af[mi], bfr[ni], acc[mi][ni], 0, 0, 0);
      }
    }
  }
  int colB = wn + l15;
  int rowB = wm + l4 * 4;
#pragma unroll
  for (int ni = 0; ni < 4; ++ni) {
    int oc = nh * 128 + colB + ni * 16;
    float bv = bias[oc];
#pragma unroll
    for (int mi = 0; mi < 4; ++mi) {
#pragma unroll
      for (int r = 0; r < 4; ++r) {
        int pix = rowB + mi * 16 + r;
        out[((size_t)(b * NN + h * WWI + pix)) * CC + oc] = f2b(acc[mi][ni][r] + bv);
      }
    }
  }
}

// ---------- generic MFMA GEMM (optionally z-batched): A[M,K] bf16, BT[N,K] bf16 ----------
// MODE 0: outb = bf16(gelu(acc+bias)); MODE 1: outf += acc+bias
template <int MODE>
__global__ __launch_bounds__(256, 2) void gemm_kernel(
    const bf16* __restrict__ A, const bf16* __restrict__ BT,
    const float* __restrict__ bias, bf16* __restrict__ outb,
    float* __restrict__ outf, int M, int N, int K,
    size_t strideAz, size_t strideBz, size_t strideOz) {
  A  += (size_t)blockIdx.z * strideAz;
  BT += (size_t)blockIdx.z * strideBz;
  __shared__ __align__(16) unsigned short As[128 * 64];
  __shared__ __align__(16) unsigned short Bsm[128 * 64];
  int m0 = blockIdx.x * 128, n0 = blockIdx.y * 128;
  int t = threadIdx.x, lane = t & 63, wid = t >> 6;
  int wm = (wid >> 1) * 64, wn = (wid & 1) * 64;
  int l15 = lane & 15, l4 = lane >> 4;
  f32x4 acc[4][4];
#pragma unroll
  for (int mi = 0; mi < 4; ++mi)
#pragma unroll
    for (int ni = 0; ni < 4; ++ni) acc[mi][ni] = (f32x4){0.f, 0.f, 0.f, 0.f};

  for (int kb = 0; kb < K; kb += 64) {
    __syncthreads();
    uint4 va[4], vb[4];
#pragma unroll
    for (int i = 0; i < 4; ++i) {
      int u = t + (i << 8);
      int row = u >> 3, j = (u & 7) ^ (row & 7);
      va[i] = *(const uint4*)(A + (size_t)(m0 + row) * K + kb + j * 8);
      vb[i] = *(const uint4*)(BT + (size_t)(n0 + row) * K + kb + j * 8);
    }
#pragma unroll
    for (int i = 0; i < 4; ++i) {
      int u = t + (i << 8);
      *(uint4*)(&As[(size_t)u * 8]) = va[i];
      *(uint4*)(&Bsm[(size_t)u * 8]) = vb[i];
    }
    __syncthreads();
#pragma unroll
    for (int s = 0; s < 2; ++s) {
      bfv8 af[4], bfr[4];
#pragma unroll
      for (int mi = 0; mi < 4; ++mi) {
        int row = wm + mi * 16 + l15;
        af[mi] = *(const bfv8*)(&As[(size_t)row * 64 + (((s * 4 + l4) ^ (row & 7)) << 3)]);
      }
#pragma unroll
      for (int ni = 0; ni < 4; ++ni) {
        int rn = wn + ni * 16 + l15;
        bfr[ni] = *(const bfv8*)(&Bsm[(size_t)rn * 64 + (((s * 4 + l4) ^ (rn & 7)) << 3)]);
      }
#pragma unroll
      for (int mi = 0; mi < 4; ++mi)
#pragma unroll
        for (int ni = 0; ni < 4; ++ni)
          acc[mi][ni] = __builtin_amdgcn_mfma_f32_16x16x32_bf16(af[mi], bfr[ni], acc[mi][ni], 0, 0, 0);
    }
  }
  int colB = n0 + wn + l15;
  int rowB = m0 + wm + l4 * 4;
#pragma unroll
  for (int ni = 0; ni < 4; ++ni) {
    int col = colB + ni * 16;
    float bv = bias[col];
#pragma unroll
    for (int mi = 0; mi < 4; ++mi) {
#pragma unroll
      for (int r = 0; r < 4; ++r) {
        int row = rowB + mi * 16 + r;
        float v = acc[mi][ni][r] + bv;
        if (MODE == 0) outb[(size_t)blockIdx.z * strideOz + (size_t)row * N + col] = f2b(gelu_exact(v));
        else outf[(size_t)blockIdx.z * strideOz + (size_t)row * N + col] += v;
      }
    }
  }
}

// ---------- slice logits + softmax over G; 16 points/block, weights in LDS ----------
__global__ __launch_bounds__(256) void slice_softmax_kernel(
    const bf16* __restrict__ xmid, const float* __restrict__ sw_w,
    const float* __restrict__ sw_b, const float* __restrict__ temp,
    bf16* __restrict__ swout) {
  __shared__ float wsm[32][64];     // 8 KiB  [d][g]
  __shared__ float xm[SSP][256];    // 16 KiB
  __shared__ float bias_s[64];
  __shared__ float rtc[8];
  int p0 = blockIdx.x * SSP;
  int t = threadIdx.x;
  for (int i = t; i < 2048; i += 256) wsm[i >> 6][i & 63] = sw_w[i];
  if (t < 64) bias_s[t] = sw_b[t];
  if (t < 8) {
    float x = temp[t];
    rtc[t] = 1.0f / fminf(fmaxf(x, 0.1f), 5.0f);
  }
  const unsigned short* xg = (const unsigned short*)xmid + (size_t)p0 * 256;
#pragma unroll
  for (int i2 = t; i2 < SSP * 32; i2 += 256) {
    uint4 v = ((const uint4*)xg)[i2];
    int p = i2 >> 5, c = (i2 & 31) << 3;
    xm[p][c + 0] = us2f((unsigned short)(v.x & 0xffff));
    xm[p][c + 1] = us2f((unsigned short)(v.x >> 16));
    xm[p][c + 2] = us2f((unsigned short)(v.y & 0xffff));
    xm[p][c + 3] = us2f((unsigned short)(v.y >> 16));
    xm[p][c + 4] = us2f((unsigned short)(v.z & 0xffff));
    xm[p][c + 5] = us2f((unsigned short)(v.z >> 16));
    xm[p][c + 6] = us2f((unsigned short)(v.w & 0xffff));
    xm[p][c + 7] = us2f((unsigned short)(v.w >> 16));
  }
  __syncthreads();
  int g = t & 63, pq = t >> 6;
  for (int pp2 = 0; pp2 < SSP / 4; ++pp2) {
    int p = pp2 * 4 + pq;
#pragma unroll
    for (int h = 0; h < NHEADS; ++h) {
      float acc = bias_s[g];
      const float* xr = &xm[p][h * 32];
#pragma unroll
      for (int d = 0; d < 32; ++d) acc += xr[d] * wsm[d][g];
      float logit = acc * rtc[h];
      float m = logit;
#pragma unroll
      for (int off = 32; off > 0; off >>= 1) m = fmaxf(m, __shfl_xor(m, off, 64));
      float e = __expf(logit - m);
      float s = e;
#pragma unroll
      for (int off = 32; off > 0; off >>= 1) s += __shfl_xor(s, off, 64);
      swout[(size_t)(p0 + p) * 512 + h * 64 + g] = f2b(e / s);
    }
  }
}

// ---------- slice reduce as split-K MFMA outer product ----------
__global__ __launch_bounds__(256) void slice_st_kernel(
    const bf16* __restrict__ fxmid, const bf16* __restrict__ sw,
    float* __restrict__ stp, float* __restrict__ normp) {
  __shared__ __align__(16) unsigned short sw_s[64 * 64];
  __shared__ __align__(16) unsigned short fx_s[32 * 64];
  __shared__ float npart[2][64];
  int split = blockIdx.x, h = blockIdx.y, b = blockIdx.z;
  int t = threadIdx.x, w = t >> 6, lane = t & 63;
  int l15 = lane & 15, q4 = lane >> 4;
  int ns0 = split * (NN / SPLIT);
  const int NT = (NN / SPLIT) / 64;
  f32x4 acc0 = {0.f, 0.f, 0.f, 0.f}, acc1 = {0.f, 0.f, 0.f, 0.f};
  float nacc = 0.f;
  const unsigned short* swg = (const unsigned short*)sw + (size_t)b * NN * 512 + h * 64;
  const unsigned short* fxg = (const unsigned short*)fxmid + (size_t)b * NN * 256 + h * 32;

  for (int kt = 0; kt < NT; ++kt) {
    int n0 = ns0 + kt * 64;
    __syncthreads();
    if (w < 2) {
      int g = lane;
#pragma unroll
      for (int i = 0; i < 4; ++i) {
        int j = w + 2 * i;
        const unsigned short* p = swg + (size_t)(n0 + j * 8) * 512 + g;
        unsigned short v0 = p[0],     v1 = p[512],  v2 = p[1024], v3 = p[1536];
        unsigned short v4 = p[2048],  v5 = p[2560], v6 = p[3072], v7 = p[3584];
        nacc += us2f(v0) + us2f(v1) + us2f(v2) + us2f(v3) +
                us2f(v4) + us2f(v5) + us2f(v6) + us2f(v7);
        uint4 pk = make_uint4((unsigned)v0 | ((unsigned)v1 << 16),
                              (unsigned)v2 | ((unsigned)v3 << 16),
                              (unsigned)v4 | ((unsigned)v5 << 16),
                              (unsigned)v6 | ((unsigned)v7 << 16));
        ((uint4*)sw_s)[g * 8 + (j ^ (g & 7))] = pk;
      }
    } else {
      int d = lane & 31, nh = lane >> 5, w3 = w - 2;
#pragma unroll
      for (int i = 0; i < 2; ++i) {
        int nbase = (w3 * 2 + i) * 16 + nh * 8;
        const unsigned short* p = fxg + (size_t)(n0 + nbase) * 256 + d;
        unsigned short v0 = p[0],    v1 = p[256],  v2 = p[512],  v3 = p[768];
        unsigned short v4 = p[1024], v5 = p[1280], v6 = p[1536], v7 = p[1792];
        uint4 pk = make_uint4((unsigned)v0 | ((unsigned)v1 << 16),
                              (unsigned)v2 | ((unsigned)v3 << 16),
                              (unsigned)v4 | ((unsigned)v5 << 16),
                              (unsigned)v6 | ((unsigned)v7 << 16));
        int u = nbase >> 3;
        ((uint4*)fx_s)[d * 8 + (u ^ (d & 7))] = pk;
      }
    }
    __syncthreads();
    int gg = w * 16 + l15;
    int d0 = l15, d1 = 16 + l15;
#pragma unroll
    for (int ks = 0; ks < 2; ++ks) {
      bfv8 af  = ((const bfv8*)sw_s)[gg * 8 + ((ks * 4 + q4) ^ (gg & 7))];
      bfv8 bf0 = ((const bfv8*)fx_s)[d0 * 8 + ((ks * 4 + q4) ^ (d0 & 7))];
      bfv8 bf1 = ((const bfv8*)fx_s)[d1 * 8 + ((ks * 4 + q4) ^ (d1 & 7))];
      acc0 = __builtin_amdgcn_mfma_f32_16x16x32_bf16(af, bf0, acc0, 0, 0, 0);
      acc1 = __builtin_amdgcn_mfma_f32_16x16x32_bf16(af, bf1, acc1, 0, 0, 0);
    }
  }
  if (w < 2) npart[w][lane] = nacc;
  __syncthreads();
  int bh = b * NHEADS + h;
  if (t < 64) normp[(size_t)split * (BB * NHEADS * GG) + bh * 64 + t] = npart[0][t] + npart[1][t];
  size_t base = ((size_t)split * (BB * NHEADS * GG) + bh * 64) * 32;
#pragma unroll
  for (int r = 0; r < 4; ++r) {
    int g = w * 16 + q4 * 4 + r;
    stp[base + (size_t)g * 32 + l15] = acc0[r];
    stp[base + (size_t)g * 32 + 16 + l15] = acc1[r];
  }
}

// ---------- attention over G=64 per (b,h); 256 threads; weights + reduction in LDS ----------
__global__ __launch_bounds__(256) void attn_kernel(
    const float* __restrict__ stp, const float* __restrict__ normp,
    const float* __restrict__ wq, const float* __restrict__ wk,
    const float* __restrict__ wv, float* __restrict__ ot) {
  __shared__ float wqs[32 * 32], wks[32 * 32], wvs[32 * 32];
  __shared__ float st[GG][DHD + 1];
  __shared__ float qq[GG][DHD + 1], kk[GG][DHD + 1], vv[GG][DHD + 1];
  __shared__ float pm[GG][GG + 1];
  __shared__ float nrm[GG];
  int bh = blockIdx.x;
  int t = threadIdx.x;
  ((float4*)wqs)[t] = ((const float4*)wq)[t];
  ((float4*)wks)[t] = ((const float4*)wk)[t];
  ((float4*)wvs)[t] = ((const float4*)wv)[t];
  if (t < 64) {
    float ns = 0.f;
    for (int s = 0; s < SPLIT; ++s) ns += normp[(size_t)s * (BB * NHEADS * GG) + bh * 64 + t];
    nrm[t] = 1.0f / (ns + 1e-5f);
  }
  __syncthreads();
#pragma unroll
  for (int i = 0; i < 8; ++i) {
    int idx = t + i * 256;
    int g = idx >> 5, d = idx & 31;
    float a = 0.f;
    for (int s = 0; s < SPLIT; ++s)
      a += stp[((size_t)s * (BB * NHEADS * GG) + bh * 64 + g) * 32 + d];
    st[g][d] = a * nrm[g];
  }
  __syncthreads();
#pragma unroll
  for (int i = 0; i < 8; ++i) {
    int idx = t + i * 256;
    int g = idx >> 5, d = idx & 31;
    float aq = 0.f, ak = 0.f, av = 0.f;
#pragma unroll
    for (int c = 0; c < 32; ++c) {
      float sv = st[g][c];
      aq += sv * wqs[c * 32 + d];
      ak += sv * wks[c * 32 + d];
      av += sv * wvs[c * 32 + d];
    }
    qq[g][d] = aq; kk[g][d] = ak; vv[g][d] = av;
  }
  __syncthreads();
  {
    int g = t >> 2, sub = t & 3;
    float sc[16];
    float m = -1e30f;
    const float scale = 0.17677669529663687f;
#pragma unroll
    for (int jj = 0; jj < 16; ++jj) {
      int j = sub * 16 + jj;
      float a = 0.f;
#pragma unroll
      for (int d = 0; d < 32; ++d) a += qq[g][d] * kk[j][d];
      a *= scale;
      sc[jj] = a;
      m = fmaxf(m, a);
    }
    m = fmaxf(m, __shfl_xor(m, 1, 64));
    m = fmaxf(m, __shfl_xor(m, 2, 64));
    float ssum = 0.f;
#pragma unroll
    for (int jj = 0; jj < 16; ++jj) { sc[jj] = __expf(sc[jj] - m); ssum += sc[jj]; }
    ssum += __shfl_xor(ssum, 1, 64);
    ssum += __shfl_xor(ssum, 2, 64);
    float rs = 1.0f / ssum;
#pragma unroll
    for (int jj = 0; jj < 16; ++jj) pm[g][sub * 16 + jj] = sc[jj] * rs;
  }
  __syncthreads();
#pragma unroll
  for (int i = 0; i < 8; ++i) {
    int idx = t + i * 256;
    int g = idx >> 5, d = idx & 31;
    float a = 0.f;
#pragma unroll
    for (int j = 0; j < GG; ++j) a += pm[g][j] * vv[j][d];
    ot[((size_t)bh * GG + g) * DHD + d] = a;
  }
}

// ---------- Wc^T[b][c][h*64+g] = sum_d ot[b,h,g,d] * wo[h*32+d, c]  (bf16 out) ----------
__global__ __launch_bounds__(256) void wc_kernel(const float* __restrict__ ot,
                                                 const float* __restrict__ wo,
                                                 bf16* __restrict__ wct) {
  __shared__ float ots[GG][DHD];   // 8 KiB
  int bh = blockIdx.x;             // b*8 + h
  int h = bh & 7, b = bh >> 3;
  int t = threadIdx.x;             // 256 = c
  for (int i = t; i < GG * DHD; i += 256) ots[i >> 5][i & 31] = ot[(size_t)bh * (GG * DHD) + i];
  float wol[DHD];
#pragma unroll
  for (int d = 0; d < DHD; ++d) wol[d] = wo[(size_t)(h * DHD + d) * CC + t];
  __syncthreads();
  bf16* dst = wct + ((size_t)b * CC + t) * (NHEADS * GG) + h * GG;
#pragma unroll 4
  for (int g = 0; g < GG; ++g) {
    float a = 0.f;
#pragma unroll
    for (int d = 0; d < DHD; ++d) a += wol[d] * ots[g][d];
    dst[g] = f2b(a);
  }
}

// ---------- final LN3 + head (C -> 4) ----------
__global__ void head_kernel(const float* __restrict__ fx, const float* __restrict__ w,
                            const float* __restrict__ b, const float* __restrict__ wout,
                            const float* __restrict__ bout, float* __restrict__ out) {
  int pp = blockIdx.x;
  int t = threadIdx.x;
  float v = fx[(size_t)pp * CC + t];
  float s = wave_sum(v);
  float sq = wave_sum(v * v);
  __shared__ float ls[4], lq[4];
  int wid = t >> 6, lane = t & 63;
  if (lane == 0) { ls[wid] = s; lq[wid] = sq; }
  __syncthreads();
  float tot = ls[0] + ls[1] + ls[2] + ls[3];
  float totq = lq[0] + lq[1] + lq[2] + lq[3];
  float mean = tot * (1.0f / CC);
  float var = totq * (1.0f / CC) - mean * mean;
  float rstd = rsqrtf(var + 1e-5f);
  float xn = (v - mean) * rstd * w[t] + b[t];
  __shared__ float xs[CC];
  xs[t] = xn;
  __syncthreads();
  if (t < 4) {
    float a = bout[t];
    for (int c = 0; c < CC; ++c) a += xs[c] * wout[c * 4 + t];
    out[(size_t)pp * 4 + t] = a;
  }
}

extern "C" void kernel_launch(void* const* d_in, const int* in_sizes, int n_in,
                              void* d_out, int out_size, void* d_ws, size_t ws_size,
                              hipStream_t stream) {
  const float* fx_in      = (const float*)d_in[0];
  const float* ln1_w      = (const float*)d_in[1];
  const float* ln1_b      = (const float*)d_in[2];
  const float* convx_w    = (const float*)d_in[3];
  const float* convx_b    = (const float*)d_in[4];
  const float* convfx_w   = (const float*)d_in[5];
  const float* convfx_b   = (const float*)d_in[6];
  const float* slice_w    = (const float*)d_in[7];
  const float* slice_b    = (const float*)d_in[8];
  const float* temperature= (const float*)d_in[9];
  const float* wq         = (const float*)d_in[10];
  const float* wk         = (const float*)d_in[11];
  const float* wv         = (const float*)d_in[12];
  const float* wo         = (const float*)d_in[13];
  const float* bo         = (const float*)d_in[14];
  const float* ln2_w      = (const float*)d_in[15];
  const float* ln2_b      = (const float*)d_in[16];
  const float* w1         = (const float*)d_in[17];
  const float* b1         = (const float*)d_in[18];
  const float* w2         = (const float*)d_in[19];
  const float* b2         = (const float*)d_in[20];
  const float* ln3_w      = (const float*)d_in[21];
  const float* ln3_b      = (const float*)d_in[22];
  const float* w_out      = (const float*)d_in[23];
  const float* b_out      = (const float*)d_in[24];
  float* out = (float*)d_out;

  char* ws = (char*)d_ws;
  size_t off = 0;
  auto alloc = [&](size_t bytes) -> void* {
    void* p = ws + off;
    off += (bytes + 255) & ~(size_t)255;
    return p;
  };
  float* fx32  = (float*)alloc((size_t)BB * NN * CC * 4);    // 64 MiB
  bf16* xln    = (bf16*)alloc((size_t)BB * NN * CC * 2);     // 32 MiB
  char* uni    = (char*)alloc((size_t)BB * NN * HIDD * 2);   // 128 MiB union region
  bf16* xmid   = (bf16*)uni;
  bf16* fxmid  = (bf16*)(uni + (size_t)BB * NN * INNERC * 2);
  bf16* swb    = (bf16*)(uni + (size_t)2 * BB * NN * INNERC * 2);
  bf16* hidden = (bf16*)uni;                                 // aliases xmid/fxmid/swb (dead by MLP)
  float* stp   = (float*)uni;                                // 8 MiB (aliases dead xmid)
  float* normp = (float*)(uni + (size_t)SPLIT * BB * NHEADS * GG * DHD * 4);
  bf16* wtx    = (bf16*)alloc((size_t)LL * 9 * CC * INNERC * 2);
  bf16* wtfx   = (bf16*)alloc((size_t)LL * 9 * CC * INNERC * 2);
  bf16* w1t    = (bf16*)alloc((size_t)LL * CC * HIDD * 2);
  bf16* w2t    = (bf16*)alloc((size_t)LL * HIDD * CC * 2);
  float* otb   = (float*)alloc((size_t)BB * NHEADS * GG * DHD * 4);
  bf16* wct    = (bf16*)alloc((size_t)BB * CC * NHEADS * GG * 2);   // 1 MiB
  (void)ws_size; (void)in_sizes; (void)n_in; (void)out_size;

  transpose_cast_kernel<<<dim3(8, 8, LL * 9), 256, 0, stream>>>(convx_w, wtx, CC, INNERC);
  transpose_cast_kernel<<<dim3(8, 8, LL * 9), 256, 0, stream>>>(convfx_w, wtfx, CC, INNERC);
  transpose_cast_kernel<<<dim3(32, 8, LL), 256, 0, stream>>>(w1, w1t, CC, HIDD);
  transpose_cast_kernel<<<dim3(8, 32, LL), 256, 0, stream>>>(w2, w2t, HIDD, CC);

  hipMemcpyAsync(fx32, fx_in, (size_t)BB * NN * CC * sizeof(float),
                 hipMemcpyDeviceToDevice, stream);

  const int M = BB * NN;  // 65536
  for (int i = 0; i < LL; ++i) {
    ln_kernel<<<M, 256, 0, stream>>>(fx32, ln1_w + i * CC, ln1_b + i * CC, xln);
    conv_mfma_kernel<<<BB * HH * 2, 256, 0, stream>>>(
        xln, wtfx + (size_t)i * 9 * CC * INNERC, convfx_b + i * INNERC, fxmid);
    conv_mfma_kernel<<<BB * HH * 2, 256, 0, stream>>>(
        xln, wtx + (size_t)i * 9 * CC * INNERC, convx_b + i * INNERC, xmid);
    slice_softmax_kernel<<<M / SSP, 256, 0, stream>>>(
        xmid, slice_w + i * DHD * GG, slice_b + i * GG, temperature + i * NHEADS, swb);
    slice_st_kernel<<<dim3(SPLIT, NHEADS, BB), 256, 0, stream>>>(fxmid, swb, stp, normp);
    attn_kernel<<<BB * NHEADS, 256, 0, stream>>>(
        stp, normp, wq + i * DHD * DHD, wk + i * DHD * DHD, wv + i * DHD * DHD, otb);
    wc_kernel<<<BB * NHEADS, 256, 0, stream>>>(otb, wo + (size_t)i * INNERC * CC, wct);
    // fx[b] += sw[b] @ Wc[b] + bo   (deslice + wo-projection fused)
    gemm_kernel<1><<<dim3(NN / 128, CC / 128, BB), 256, 0, stream>>>(
        swb, wct, bo + i * CC, nullptr, fx32, NN, CC, NHEADS * GG,
        (size_t)NN * (NHEADS * GG), (size_t)CC * (NHEADS * GG), (size_t)NN * CC);
    ln_kernel<<<M, 256, 0, stream>>>(fx32, ln2_w + i * CC, ln2_b + i * CC, xln);
    gemm_kernel<0><<<dim3(M / 128, HIDD / 128, 1), 256, 0, stream>>>(
        xln, w1t + (size_t)i * CC * HIDD, b1 + i * HIDD, hidden, nullptr, M, HIDD, CC, 0, 0, 0);
    gemm_kernel<1><<<dim3(M / 128, CC / 128, 1), 256, 0, stream>>>(
        hidden, w2t + (size_t)i * HIDD * CC, b2 + i * CC, nullptr, fx32, M, CC, HIDD, 0, 0, 0);
  }
  head_kernel<<<M, 256, 0, stream>>>(fx32, ln3_w, ln3_b, w_out, b_out, out);
}

// Round 7
// 2956.835 us; speedup vs baseline: 7.8543x; 1.0786x over previous
//
#include <hip/hip_runtime.h>
#include <hip/hip_bf16.h>

typedef __hip_bfloat16 bf16;
typedef __bf16 bfv8 __attribute__((ext_vector_type(8)));
typedef float f32x4 __attribute__((ext_vector_type(4)));

#define BB 4
#define HH 128
#define WWI 128
#define NN 16384      // HH*WWI
#define CC 256
#define LL 4
#define NHEADS 8
#define DHD 32
#define GG 64
#define INNERC 256    // NHEADS*DHD
#define HIDD 1024
#define SPLIT 32      // split-K blocks per (b,h) in slice_st
#define SSP 16        // points per block in slice_softmax

__device__ __forceinline__ float b2f(bf16 x) { return __bfloat162float(x); }
__device__ __forceinline__ bf16 f2b(float x) { return __float2bfloat16(x); }
__device__ __forceinline__ float us2f(unsigned short v) {
  return __uint_as_float(((unsigned)v) << 16);
}

__device__ __forceinline__ float wave_sum(float v) {
#pragma unroll
  for (int off = 32; off > 0; off >>= 1) v += __shfl_down(v, off, 64);
  return v;
}

__device__ __forceinline__ float gelu_exact(float x) {
  return 0.5f * x * (1.0f + erff(x * 0.70710678118654752f));
}

// ---------- batched transpose+cast: src fp32 [T][R][Cm] -> dst bf16 [T][Cm][R] ----------
__global__ void transpose_cast_kernel(const float* __restrict__ src, bf16* __restrict__ dst,
                                      int R, int Cm) {
  __shared__ float tile[32][33];
  int tb = blockIdx.z;
  const float* s = src + (size_t)tb * R * Cm;
  bf16* d = dst + (size_t)tb * R * Cm;
  int c0 = blockIdx.x * 32, r0 = blockIdx.y * 32;
  int tx = threadIdx.x & 31, ty = threadIdx.x >> 5;  // 32 x 8
  for (int rr = ty; rr < 32; rr += 8) {
    int r = r0 + rr, c = c0 + tx;
    tile[rr][tx] = (r < R && c < Cm) ? s[(size_t)r * Cm + c] : 0.f;
  }
  __syncthreads();
  for (int cc = ty; cc < 32; cc += 8) {
    int c = c0 + cc, r = r0 + tx;
    if (c < Cm && r < R) d[(size_t)c * R + r] = f2b(tile[tx][cc]);
  }
}

// ---------- LayerNorm over C=256 per point; block = 256 threads ----------
__global__ void ln_kernel(const float* __restrict__ x, const float* __restrict__ w,
                          const float* __restrict__ b, bf16* __restrict__ out) {
  int pp = blockIdx.x;
  int t = threadIdx.x;
  float v = x[(size_t)pp * CC + t];
  float s = wave_sum(v);
  float sq = wave_sum(v * v);
  __shared__ float ls[4], lq[4];
  int wid = t >> 6, lane = t & 63;
  if (lane == 0) { ls[wid] = s; lq[wid] = sq; }
  __syncthreads();
  float tot = ls[0] + ls[1] + ls[2] + ls[3];
  float totq = lq[0] + lq[1] + lq[2] + lq[3];
  float mean = tot * (1.0f / CC);
  float var = totq * (1.0f / CC) - mean * mean;
  float rstd = rsqrtf(var + 1e-5f);
  float o = (v - mean) * rstd * w[t] + b[t];
  out[(size_t)pp * CC + t] = f2b(o);
}

// ---------- 3x3 conv as implicit MFMA GEMM ----------
__global__ __launch_bounds__(256, 2) void conv_mfma_kernel(
    const bf16* __restrict__ xln, const bf16* __restrict__ wt,
    const float* __restrict__ bias, bf16* __restrict__ out) {
  __shared__ __align__(16) unsigned short As[3 * 130 * 64];
  __shared__ __align__(16) unsigned short Bsm[128 * 64];
  int bid = blockIdx.x;
  int nh = bid & 1;
  int h = (bid >> 1) & 127;
  int b = bid >> 8;
  int t = threadIdx.x, lane = t & 63, wid = t >> 6;
  int wm = (wid >> 1) * 64, wn = (wid & 1) * 64;
  int l15 = lane & 15, l4 = lane >> 4;
  f32x4 acc[4][4];
#pragma unroll
  for (int mi = 0; mi < 4; ++mi)
#pragma unroll
    for (int ni = 0; ni < 4; ++ni) acc[mi][ni] = (f32x4){0.f, 0.f, 0.f, 0.f};
  const bf16* xbase = xln + (size_t)b * NN * CC;

  for (int q = 0; q < 4; ++q) {
    __syncthreads();
    for (int u = t; u < 3120; u += 256) {
      int jp = u & 7;
      int pc = u >> 3;
      int r = pc / 130, cl = pc - r * 130;
      int j = jp ^ (cl & 7);
      int gr = h + r - 1, gc = cl - 1;
      uint4 v = make_uint4(0u, 0u, 0u, 0u);
      if ((unsigned)gr < 128u && (unsigned)gc < 128u)
        v = *(const uint4*)(xbase + ((size_t)(gr * WWI + gc)) * CC + q * 64 + j * 8);
      *(uint4*)(&As[(size_t)u * 8]) = v;
    }
    for (int tap = 0; tap < 9; ++tap) {
      if (tap > 0) __syncthreads();
      {
        const bf16* wsrc = wt + ((size_t)tap * 256 + nh * 128) * 256 + q * 64;
#pragma unroll
        for (int i = 0; i < 4; ++i) {
          int u = t + (i << 8);
          int n = u >> 3, jp = u & 7, j = jp ^ (n & 7);
          uint4 v = *(const uint4*)(wsrc + (size_t)n * 256 + j * 8);
          *(uint4*)(&Bsm[(size_t)u * 8]) = v;
        }
      }
      __syncthreads();
      int ky = tap / 3, kx = tap - ky * 3;
#pragma unroll
      for (int s = 0; s < 2; ++s) {
        bfv8 af[4], bfr[4];
#pragma unroll
        for (int mi = 0; mi < 4; ++mi) {
          int cl = wm + mi * 16 + l15 + kx;
          af[mi] = *(const bfv8*)(&As[((size_t)(ky * 130 + cl)) * 64 +
                                      (((s * 4 + l4) ^ (cl & 7)) << 3)]);
        }
#pragma unroll
        for (int ni = 0; ni < 4; ++ni) {
          int rn = wn + ni * 16 + l15;
          bfr[ni] = *(const bfv8*)(&Bsm[(size_t)rn * 64 + (((s * 4 + l4) ^ (rn & 7)) << 3)]);
        }
#pragma unroll
        for (int mi = 0; mi < 4; ++mi)
#pragma unroll
          for (int ni = 0; ni < 4; ++ni)
            acc[mi][ni] = __builtin_amdgcn_mfma_f32_16x16x32_bf16(af[mi], bfr[ni], acc[mi][ni], 0, 0, 0);
      }
    }
  }
  int colB = wn + l15;
  int rowB = wm + l4 * 4;
#pragma unroll
  for (int ni = 0; ni < 4; ++ni) {
    int oc = nh * 128 + colB + ni * 16;
    float bv = bias[oc];
#pragma unroll
    for (int mi = 0; mi < 4; ++mi) {
#pragma unroll
      for (int r = 0; r < 4; ++r) {
        int pix = rowB + mi * 16 + r;
        out[((size_t)(b * NN + h * WWI + pix)) * CC + oc] = f2b(acc[mi][ni][r] + bv);
      }
    }
  }
}

// ---------- generic MFMA GEMM (z-batched), MODE 1 only: outf += acc + bias ----------
__global__ __launch_bounds__(256, 2) void gemm_acc_kernel(
    const bf16* __restrict__ A, const bf16* __restrict__ BT,
    const float* __restrict__ bias, float* __restrict__ outf,
    int M, int N, int K, size_t strideAz, size_t strideBz, size_t strideOz) {
  A  += (size_t)blockIdx.z * strideAz;
  BT += (size_t)blockIdx.z * strideBz;
  __shared__ __align__(16) unsigned short As[128 * 64];
  __shared__ __align__(16) unsigned short Bsm[128 * 64];
  int m0 = blockIdx.x * 128, n0 = blockIdx.y * 128;
  int t = threadIdx.x, lane = t & 63, wid = t >> 6;
  int wm = (wid >> 1) * 64, wn = (wid & 1) * 64;
  int l15 = lane & 15, l4 = lane >> 4;
  f32x4 acc[4][4];
#pragma unroll
  for (int mi = 0; mi < 4; ++mi)
#pragma unroll
    for (int ni = 0; ni < 4; ++ni) acc[mi][ni] = (f32x4){0.f, 0.f, 0.f, 0.f};

  for (int kb = 0; kb < K; kb += 64) {
    __syncthreads();
    uint4 va[4], vb[4];
#pragma unroll
    for (int i = 0; i < 4; ++i) {
      int u = t + (i << 8);
      int row = u >> 3, j = (u & 7) ^ (row & 7);
      va[i] = *(const uint4*)(A + (size_t)(m0 + row) * K + kb + j * 8);
      vb[i] = *(const uint4*)(BT + (size_t)(n0 + row) * K + kb + j * 8);
    }
#pragma unroll
    for (int i = 0; i < 4; ++i) {
      int u = t + (i << 8);
      *(uint4*)(&As[(size_t)u * 8]) = va[i];
      *(uint4*)(&Bsm[(size_t)u * 8]) = vb[i];
    }
    __syncthreads();
#pragma unroll
    for (int s = 0; s < 2; ++s) {
      bfv8 af[4], bfr[4];
#pragma unroll
      for (int mi = 0; mi < 4; ++mi) {
        int row = wm + mi * 16 + l15;
        af[mi] = *(const bfv8*)(&As[(size_t)row * 64 + (((s * 4 + l4) ^ (row & 7)) << 3)]);
      }
#pragma unroll
      for (int ni = 0; ni < 4; ++ni) {
        int rn = wn + ni * 16 + l15;
        bfr[ni] = *(const bfv8*)(&Bsm[(size_t)rn * 64 + (((s * 4 + l4) ^ (rn & 7)) << 3)]);
      }
#pragma unroll
      for (int mi = 0; mi < 4; ++mi)
#pragma unroll
        for (int ni = 0; ni < 4; ++ni)
          acc[mi][ni] = __builtin_amdgcn_mfma_f32_16x16x32_bf16(af[mi], bfr[ni], acc[mi][ni], 0, 0, 0);
    }
  }
  int colB = n0 + wn + l15;
  int rowB = m0 + wm + l4 * 4;
#pragma unroll
  for (int ni = 0; ni < 4; ++ni) {
    int col = colB + ni * 16;
    float bv = bias[col];
#pragma unroll
    for (int mi = 0; mi < 4; ++mi) {
#pragma unroll
      for (int r = 0; r < 4; ++r) {
        int row = rowB + mi * 16 + r;
        outf[(size_t)blockIdx.z * strideOz + (size_t)row * N + col] += acc[mi][ni][r] + bv;
      }
    }
  }
}

// ---------- fused MLP: fx += gelu(xln@w1+b1)@w2+b2 ; hidden never leaves the CU ----------
// block = 512 threads (8 waves), 128 rows x full C=256 out per block.
__global__ __launch_bounds__(512, 2) void mlp_fused_kernel(
    const bf16* __restrict__ xln, const bf16* __restrict__ w1t,
    const float* __restrict__ b1, const bf16* __restrict__ w2t,
    const float* __restrict__ b2, float* __restrict__ fx) {
  __shared__ __align__(16) unsigned short As[128 * 256];  // 64 KiB, xln tile (per-64 XOR swizzle)
  __shared__ __align__(16) bf16 Hs[128 * 128];            // 32 KiB, one hidden chunk
  __shared__ __align__(16) unsigned short Wb[256 * 64];   // 32 KiB, weight staging
  int m0 = blockIdx.x * 128;
  int t = threadIdx.x, lane = t & 63, wid = t >> 6;
  int l15 = lane & 15, q4 = lane >> 4;
  // GEMM1 wave tile: 64m x 32n;  GEMM2 wave tile: 64m x 64n
  int wm2 = (wid & 1) * 64, wn2 = (wid >> 1) * 32;
  int wm = (wid & 1) * 64, wn = (wid >> 1) * 64;

  // stage A (xln rows m0..m0+127, full K=256) — globally contiguous
  const unsigned short* xg = (const unsigned short*)xln + (size_t)m0 * 256;
#pragma unroll
  for (int i = 0; i < 8; ++i) {
    int u = t + i * 512;                  // 4096 vec writes
    int row = u >> 5, v = u & 31;
    int kb = v >> 3, jp = v & 7;
    uint4 val = ((const uint4*)xg)[u];
    ((uint4*)As)[row * 32 + kb * 8 + (jp ^ (row & 7))] = val;
  }

  f32x4 accO[4][4];
#pragma unroll
  for (int mi = 0; mi < 4; ++mi)
#pragma unroll
    for (int ni = 0; ni < 4; ++ni) accO[mi][ni] = (f32x4){0.f, 0.f, 0.f, 0.f};

  for (int j = 0; j < 8; ++j) {           // hidden chunks of 128
    int hbase = j * 128;
    f32x4 acc2[4][2];
#pragma unroll
    for (int mi = 0; mi < 4; ++mi)
#pragma unroll
      for (int nj = 0; nj < 2; ++nj) acc2[mi][nj] = (f32x4){0.f, 0.f, 0.f, 0.f};
    // ---- GEMM1: hidden chunk = A @ W1[:, hbase:hbase+128] ----
    for (int kb = 0; kb < 4; ++kb) {
      __syncthreads();                    // prev compute done before Wb overwrite
#pragma unroll
      for (int i = 0; i < 2; ++i) {       // stage W1T chunk [128 n][64 k] = 16 KiB
        int u = t + i * 512;
        int n = u >> 3, jp = u & 7;
        uint4 val = *(const uint4*)(w1t + (size_t)(hbase + n) * 256 + kb * 64 + jp * 8);
        ((uint4*)Wb)[n * 8 + (jp ^ (n & 7))] = val;
      }
      __syncthreads();
#pragma unroll
      for (int ks = 0; ks < 2; ++ks) {
        int kgrp = ks * 4 + q4;
        bfv8 af[4], bfr[2];
#pragma unroll
        for (int mi = 0; mi < 4; ++mi) {
          int row = wm2 + mi * 16 + l15;
          af[mi] = *(const bfv8*)(&As[row * 256 + kb * 64 + ((kgrp ^ (row & 7)) << 3)]);
        }
#pragma unroll
        for (int nj = 0; nj < 2; ++nj) {
          int n = wn2 + nj * 16 + l15;
          bfr[nj] = *(const bfv8*)(&Wb[n * 64 + ((kgrp ^ (n & 7)) << 3)]);
        }
#pragma unroll
        for (int mi = 0; mi < 4; ++mi)
#pragma unroll
          for (int nj = 0; nj < 2; ++nj)
            acc2[mi][nj] = __builtin_amdgcn_mfma_f32_16x16x32_bf16(af[mi], bfr[nj], acc2[mi][nj], 0, 0, 0);
      }
    }
    // ---- +b1, gelu, pack to Hs (bf16) ----
#pragma unroll
    for (int nj = 0; nj < 2; ++nj) {
      int coln = wn2 + nj * 16 + l15;
      float bv = b1[hbase + coln];
      int half = coln >> 6, sub = (coln >> 3) & 7, lo = coln & 7;
#pragma unroll
      for (int mi = 0; mi < 4; ++mi) {
#pragma unroll
        for (int r = 0; r < 4; ++r) {
          int row = wm2 + mi * 16 + q4 * 4 + r;
          float v = acc2[mi][nj][r] + bv;
          Hs[row * 128 + half * 64 + (((sub ^ (row & 7)) << 3) + lo)] = f2b(gelu_exact(v));
        }
      }
    }
    // ---- GEMM2: out += H @ W2[hbase:hbase+128, :] ----
    for (int kb2 = 0; kb2 < 2; ++kb2) {
      __syncthreads();                    // Hs writes visible; prev compute done
#pragma unroll
      for (int i = 0; i < 4; ++i) {       // stage W2T chunk [256 n][64 k] = 32 KiB
        int u = t + i * 512;
        int n = u >> 3, jp = u & 7;
        uint4 val = *(const uint4*)(w2t + (size_t)n * 1024 + hbase + kb2 * 64 + jp * 8);
        ((uint4*)Wb)[n * 8 + (jp ^ (n & 7))] = val;
      }
      __syncthreads();
#pragma unroll
      for (int ks = 0; ks < 2; ++ks) {
        int kgrp = ks * 4 + q4;
        bfv8 af[4], bfr[4];
#pragma unroll
        for (int mi = 0; mi < 4; ++mi) {
          int row = wm + mi * 16 + l15;
          af[mi] = *(const bfv8*)(&Hs[row * 128 + kb2 * 64 + ((kgrp ^ (row & 7)) << 3)]);
        }
#pragma unroll
        for (int ni = 0; ni < 4; ++ni) {
          int n = wn + ni * 16 + l15;
          bfr[ni] = *(const bfv8*)(&Wb[n * 64 + ((kgrp ^ (n & 7)) << 3)]);
        }
#pragma unroll
        for (int mi = 0; mi < 4; ++mi)
#pragma unroll
          for (int ni = 0; ni < 4; ++ni)
            accO[mi][ni] = __builtin_amdgcn_mfma_f32_16x16x32_bf16(af[mi], bfr[ni], accO[mi][ni], 0, 0, 0);
      }
    }
  }
  // ---- epilogue: fx += accO + b2 ----
#pragma unroll
  for (int ni = 0; ni < 4; ++ni) {
    int col = wn + ni * 16 + l15;
    float bv = b2[col];
#pragma unroll
    for (int mi = 0; mi < 4; ++mi) {
#pragma unroll
      for (int r = 0; r < 4; ++r) {
        int row = m0 + wm + mi * 16 + q4 * 4 + r;
        fx[(size_t)row * 256 + col] += accO[mi][ni][r] + bv;
      }
    }
  }
}

// ---------- slice logits + softmax over G; 16 points/block, weights in LDS ----------
__global__ __launch_bounds__(256) void slice_softmax_kernel(
    const bf16* __restrict__ xmid, const float* __restrict__ sw_w,
    const float* __restrict__ sw_b, const float* __restrict__ temp,
    bf16* __restrict__ swout) {
  __shared__ float wsm[32][64];     // 8 KiB  [d][g]
  __shared__ float xm[SSP][256];    // 16 KiB
  __shared__ float bias_s[64];
  __shared__ float rtc[8];
  int p0 = blockIdx.x * SSP;
  int t = threadIdx.x;
  for (int i = t; i < 2048; i += 256) wsm[i >> 6][i & 63] = sw_w[i];
  if (t < 64) bias_s[t] = sw_b[t];
  if (t < 8) {
    float x = temp[t];
    rtc[t] = 1.0f / fminf(fmaxf(x, 0.1f), 5.0f);
  }
  const unsigned short* xg = (const unsigned short*)xmid + (size_t)p0 * 256;
#pragma unroll
  for (int i2 = t; i2 < SSP * 32; i2 += 256) {
    uint4 v = ((const uint4*)xg)[i2];
    int p = i2 >> 5, c = (i2 & 31) << 3;
    xm[p][c + 0] = us2f((unsigned short)(v.x & 0xffff));
    xm[p][c + 1] = us2f((unsigned short)(v.x >> 16));
    xm[p][c + 2] = us2f((unsigned short)(v.y & 0xffff));
    xm[p][c + 3] = us2f((unsigned short)(v.y >> 16));
    xm[p][c + 4] = us2f((unsigned short)(v.z & 0xffff));
    xm[p][c + 5] = us2f((unsigned short)(v.z >> 16));
    xm[p][c + 6] = us2f((unsigned short)(v.w & 0xffff));
    xm[p][c + 7] = us2f((unsigned short)(v.w >> 16));
  }
  __syncthreads();
  int g = t & 63, pq = t >> 6;
  for (int pp2 = 0; pp2 < SSP / 4; ++pp2) {
    int p = pp2 * 4 + pq;
#pragma unroll
    for (int h = 0; h < NHEADS; ++h) {
      float acc = bias_s[g];
      const float* xr = &xm[p][h * 32];
#pragma unroll
      for (int d = 0; d < 32; ++d) acc += xr[d] * wsm[d][g];
      float logit = acc * rtc[h];
      float m = logit;
#pragma unroll
      for (int off = 32; off > 0; off >>= 1) m = fmaxf(m, __shfl_xor(m, off, 64));
      float e = __expf(logit - m);
      float s = e;
#pragma unroll
      for (int off = 32; off > 0; off >>= 1) s += __shfl_xor(s, off, 64);
      swout[(size_t)(p0 + p) * 512 + h * 64 + g] = f2b(e / s);
    }
  }
}

// ---------- slice reduce as split-K MFMA outer product ----------
__global__ __launch_bounds__(256) void slice_st_kernel(
    const bf16* __restrict__ fxmid, const bf16* __restrict__ sw,
    float* __restrict__ stp, float* __restrict__ normp) {
  __shared__ __align__(16) unsigned short sw_s[64 * 64];
  __shared__ __align__(16) unsigned short fx_s[32 * 64];
  __shared__ float npart[2][64];
  int split = blockIdx.x, h = blockIdx.y, b = blockIdx.z;
  int t = threadIdx.x, w = t >> 6, lane = t & 63;
  int l15 = lane & 15, q4 = lane >> 4;
  int ns0 = split * (NN / SPLIT);
  const int NT = (NN / SPLIT) / 64;
  f32x4 acc0 = {0.f, 0.f, 0.f, 0.f}, acc1 = {0.f, 0.f, 0.f, 0.f};
  float nacc = 0.f;
  const unsigned short* swg = (const unsigned short*)sw + (size_t)b * NN * 512 + h * 64;
  const unsigned short* fxg = (const unsigned short*)fxmid + (size_t)b * NN * 256 + h * 32;

  for (int kt = 0; kt < NT; ++kt) {
    int n0 = ns0 + kt * 64;
    __syncthreads();
    if (w < 2) {
      int g = lane;
#pragma unroll
      for (int i = 0; i < 4; ++i) {
        int j = w + 2 * i;
        const unsigned short* p = swg + (size_t)(n0 + j * 8) * 512 + g;
        unsigned short v0 = p[0],     v1 = p[512],  v2 = p[1024], v3 = p[1536];
        unsigned short v4 = p[2048],  v5 = p[2560], v6 = p[3072], v7 = p[3584];
        nacc += us2f(v0) + us2f(v1) + us2f(v2) + us2f(v3) +
                us2f(v4) + us2f(v5) + us2f(v6) + us2f(v7);
        uint4 pk = make_uint4((unsigned)v0 | ((unsigned)v1 << 16),
                              (unsigned)v2 | ((unsigned)v3 << 16),
                              (unsigned)v4 | ((unsigned)v5 << 16),
                              (unsigned)v6 | ((unsigned)v7 << 16));
        ((uint4*)sw_s)[g * 8 + (j ^ (g & 7))] = pk;
      }
    } else {
      int d = lane & 31, nh = lane >> 5, w3 = w - 2;
#pragma unroll
      for (int i = 0; i < 2; ++i) {
        int nbase = (w3 * 2 + i) * 16 + nh * 8;
        const unsigned short* p = fxg + (size_t)(n0 + nbase) * 256 + d;
        unsigned short v0 = p[0],    v1 = p[256],  v2 = p[512],  v3 = p[768];
        unsigned short v4 = p[1024], v5 = p[1280], v6 = p[1536], v7 = p[1792];
        uint4 pk = make_uint4((unsigned)v0 | ((unsigned)v1 << 16),
                              (unsigned)v2 | ((unsigned)v3 << 16),
                              (unsigned)v4 | ((unsigned)v5 << 16),
                              (unsigned)v6 | ((unsigned)v7 << 16));
        int u = nbase >> 3;
        ((uint4*)fx_s)[d * 8 + (u ^ (d & 7))] = pk;
      }
    }
    __syncthreads();
    int gg = w * 16 + l15;
    int d0 = l15, d1 = 16 + l15;
#pragma unroll
    for (int ks = 0; ks < 2; ++ks) {
      bfv8 af  = ((const bfv8*)sw_s)[gg * 8 + ((ks * 4 + q4) ^ (gg & 7))];
      bfv8 bf0 = ((const bfv8*)fx_s)[d0 * 8 + ((ks * 4 + q4) ^ (d0 & 7))];
      bfv8 bf1 = ((const bfv8*)fx_s)[d1 * 8 + ((ks * 4 + q4) ^ (d1 & 7))];
      acc0 = __builtin_amdgcn_mfma_f32_16x16x32_bf16(af, bf0, acc0, 0, 0, 0);
      acc1 = __builtin_amdgcn_mfma_f32_16x16x32_bf16(af, bf1, acc1, 0, 0, 0);
    }
  }
  if (w < 2) npart[w][lane] = nacc;
  __syncthreads();
  int bh = b * NHEADS + h;
  if (t < 64) normp[(size_t)split * (BB * NHEADS * GG) + bh * 64 + t] = npart[0][t] + npart[1][t];
  size_t base = ((size_t)split * (BB * NHEADS * GG) + bh * 64) * 32;
#pragma unroll
  for (int r = 0; r < 4; ++r) {
    int g = w * 16 + q4 * 4 + r;
    stp[base + (size_t)g * 32 + l15] = acc0[r];
    stp[base + (size_t)g * 32 + 16 + l15] = acc1[r];
  }
}

// ---------- attention over G=64 per (b,h); 256 threads; weights + reduction in LDS ----------
__global__ __launch_bounds__(256) void attn_kernel(
    const float* __restrict__ stp, const float* __restrict__ normp,
    const float* __restrict__ wq, const float* __restrict__ wk,
    const float* __restrict__ wv, float* __restrict__ ot) {
  __shared__ float wqs[32 * 32], wks[32 * 32], wvs[32 * 32];
  __shared__ float st[GG][DHD + 1];
  __shared__ float qq[GG][DHD + 1], kk[GG][DHD + 1], vv[GG][DHD + 1];
  __shared__ float pm[GG][GG + 1];
  __shared__ float nrm[GG];
  int bh = blockIdx.x;
  int t = threadIdx.x;
  ((float4*)wqs)[t] = ((const float4*)wq)[t];
  ((float4*)wks)[t] = ((const float4*)wk)[t];
  ((float4*)wvs)[t] = ((const float4*)wv)[t];
  if (t < 64) {
    float ns = 0.f;
    for (int s = 0; s < SPLIT; ++s) ns += normp[(size_t)s * (BB * NHEADS * GG) + bh * 64 + t];
    nrm[t] = 1.0f / (ns + 1e-5f);
  }
  __syncthreads();
#pragma unroll
  for (int i = 0; i < 8; ++i) {
    int idx = t + i * 256;
    int g = idx >> 5, d = idx & 31;
    float a = 0.f;
    for (int s = 0; s < SPLIT; ++s)
      a += stp[((size_t)s * (BB * NHEADS * GG) + bh * 64 + g) * 32 + d];
    st[g][d] = a * nrm[g];
  }
  __syncthreads();
#pragma unroll
  for (int i = 0; i < 8; ++i) {
    int idx = t + i * 256;
    int g = idx >> 5, d = idx & 31;
    float aq = 0.f, ak = 0.f, av = 0.f;
#pragma unroll
    for (int c = 0; c < 32; ++c) {
      float sv = st[g][c];
      aq += sv * wqs[c * 32 + d];
      ak += sv * wks[c * 32 + d];
      av += sv * wvs[c * 32 + d];
    }
    qq[g][d] = aq; kk[g][d] = ak; vv[g][d] = av;
  }
  __syncthreads();
  {
    int g = t >> 2, sub = t & 3;
    float sc[16];
    float m = -1e30f;
    const float scale = 0.17677669529663687f;
#pragma unroll
    for (int jj = 0; jj < 16; ++jj) {
      int j = sub * 16 + jj;
      float a = 0.f;
#pragma unroll
      for (int d = 0; d < 32; ++d) a += qq[g][d] * kk[j][d];
      a *= scale;
      sc[jj] = a;
      m = fmaxf(m, a);
    }
    m = fmaxf(m, __shfl_xor(m, 1, 64));
    m = fmaxf(m, __shfl_xor(m, 2, 64));
    float ssum = 0.f;
#pragma unroll
    for (int jj = 0; jj < 16; ++jj) { sc[jj] = __expf(sc[jj] - m); ssum += sc[jj]; }
    ssum += __shfl_xor(ssum, 1, 64);
    ssum += __shfl_xor(ssum, 2, 64);
    float rs = 1.0f / ssum;
#pragma unroll
    for (int jj = 0; jj < 16; ++jj) pm[g][sub * 16 + jj] = sc[jj] * rs;
  }
  __syncthreads();
#pragma unroll
  for (int i = 0; i < 8; ++i) {
    int idx = t + i * 256;
    int g = idx >> 5, d = idx & 31;
    float a = 0.f;
#pragma unroll
    for (int j = 0; j < GG; ++j) a += pm[g][j] * vv[j][d];
    ot[((size_t)bh * GG + g) * DHD + d] = a;
  }
}

// ---------- Wc^T[b][c][h*64+g] = sum_d ot[b,h,g,d] * wo[h*32+d, c]  (bf16 out) ----------
__global__ __launch_bounds__(256) void wc_kernel(const float* __restrict__ ot,
                                                 const float* __restrict__ wo,
                                                 bf16* __restrict__ wct) {
  __shared__ float ots[GG][DHD];   // 8 KiB
  int bh = blockIdx.x;             // b*8 + h
  int h = bh & 7, b = bh >> 3;
  int t = threadIdx.x;             // 256 = c
  for (int i = t; i < GG * DHD; i += 256) ots[i >> 5][i & 31] = ot[(size_t)bh * (GG * DHD) + i];
  float wol[DHD];
#pragma unroll
  for (int d = 0; d < DHD; ++d) wol[d] = wo[(size_t)(h * DHD + d) * CC + t];
  __syncthreads();
  bf16* dst = wct + ((size_t)b * CC + t) * (NHEADS * GG) + h * GG;
#pragma unroll 4
  for (int g = 0; g < GG; ++g) {
    float a = 0.f;
#pragma unroll
    for (int d = 0; d < DHD; ++d) a += wol[d] * ots[g][d];
    dst[g] = f2b(a);
  }
}

// ---------- final LN3 + head (C -> 4) ----------
__global__ void head_kernel(const float* __restrict__ fx, const float* __restrict__ w,
                            const float* __restrict__ b, const float* __restrict__ wout,
                            const float* __restrict__ bout, float* __restrict__ out) {
  int pp = blockIdx.x;
  int t = threadIdx.x;
  float v = fx[(size_t)pp * CC + t];
  float s = wave_sum(v);
  float sq = wave_sum(v * v);
  __shared__ float ls[4], lq[4];
  int wid = t >> 6, lane = t & 63;
  if (lane == 0) { ls[wid] = s; lq[wid] = sq; }
  __syncthreads();
  float tot = ls[0] + ls[1] + ls[2] + ls[3];
  float totq = lq[0] + lq[1] + lq[2] + lq[3];
  float mean = tot * (1.0f / CC);
  float var = totq * (1.0f / CC) - mean * mean;
  float rstd = rsqrtf(var + 1e-5f);
  float xn = (v - mean) * rstd * w[t] + b[t];
  __shared__ float xs[CC];
  xs[t] = xn;
  __syncthreads();
  if (t < 4) {
    float a = bout[t];
    for (int c = 0; c < CC; ++c) a += xs[c] * wout[c * 4 + t];
    out[(size_t)pp * 4 + t] = a;
  }
}

extern "C" void kernel_launch(void* const* d_in, const int* in_sizes, int n_in,
                              void* d_out, int out_size, void* d_ws, size_t ws_size,
                              hipStream_t stream) {
  const float* fx_in      = (const float*)d_in[0];
  const float* ln1_w      = (const float*)d_in[1];
  const float* ln1_b      = (const float*)d_in[2];
  const float* convx_w    = (const float*)d_in[3];
  const float* convx_b    = (const float*)d_in[4];
  const float* convfx_w   = (const float*)d_in[5];
  const float* convfx_b   = (const float*)d_in[6];
  const float* slice_w    = (const float*)d_in[7];
  const float* slice_b    = (const float*)d_in[8];
  const float* temperature= (const float*)d_in[9];
  const float* wq         = (const float*)d_in[10];
  const float* wk         = (const float*)d_in[11];
  const float* wv         = (const float*)d_in[12];
  const float* wo         = (const float*)d_in[13];
  const float* bo         = (const float*)d_in[14];
  const float* ln2_w      = (const float*)d_in[15];
  const float* ln2_b      = (const float*)d_in[16];
  const float* w1         = (const float*)d_in[17];
  const float* b1         = (const float*)d_in[18];
  const float* w2         = (const float*)d_in[19];
  const float* b2         = (const float*)d_in[20];
  const float* ln3_w      = (const float*)d_in[21];
  const float* ln3_b      = (const float*)d_in[22];
  const float* w_out      = (const float*)d_in[23];
  const float* b_out      = (const float*)d_in[24];
  float* out = (float*)d_out;

  char* ws = (char*)d_ws;
  size_t off = 0;
  auto alloc = [&](size_t bytes) -> void* {
    void* p = ws + off;
    off += (bytes + 255) & ~(size_t)255;
    return p;
  };
  float* fx32  = (float*)alloc((size_t)BB * NN * CC * 4);    // 64 MiB
  bf16* xln    = (bf16*)alloc((size_t)BB * NN * CC * 2);     // 32 MiB
  char* uni    = (char*)alloc((size_t)BB * NN * 512 * 2 * 2);// xmid/fxmid/swb region
  bf16* xmid   = (bf16*)uni;
  bf16* fxmid  = (bf16*)(uni + (size_t)BB * NN * INNERC * 2);
  bf16* swb    = (bf16*)(uni + (size_t)2 * BB * NN * INNERC * 2);
  float* stp   = (float*)uni;                                // 8 MiB (aliases dead xmid)
  float* normp = (float*)(uni + (size_t)SPLIT * BB * NHEADS * GG * DHD * 4);
  bf16* wtx    = (bf16*)alloc((size_t)LL * 9 * CC * INNERC * 2);
  bf16* wtfx   = (bf16*)alloc((size_t)LL * 9 * CC * INNERC * 2);
  bf16* w1t    = (bf16*)alloc((size_t)LL * CC * HIDD * 2);
  bf16* w2t    = (bf16*)alloc((size_t)LL * HIDD * CC * 2);
  float* otb   = (float*)alloc((size_t)BB * NHEADS * GG * DHD * 4);
  bf16* wct    = (bf16*)alloc((size_t)BB * CC * NHEADS * GG * 2);   // 1 MiB
  (void)ws_size; (void)in_sizes; (void)n_in; (void)out_size;

  transpose_cast_kernel<<<dim3(8, 8, LL * 9), 256, 0, stream>>>(convx_w, wtx, CC, INNERC);
  transpose_cast_kernel<<<dim3(8, 8, LL * 9), 256, 0, stream>>>(convfx_w, wtfx, CC, INNERC);
  transpose_cast_kernel<<<dim3(32, 8, LL), 256, 0, stream>>>(w1, w1t, CC, HIDD);
  transpose_cast_kernel<<<dim3(8, 32, LL), 256, 0, stream>>>(w2, w2t, HIDD, CC);

  hipMemcpyAsync(fx32, fx_in, (size_t)BB * NN * CC * sizeof(float),
                 hipMemcpyDeviceToDevice, stream);

  const int M = BB * NN;  // 65536
  for (int i = 0; i < LL; ++i) {
    ln_kernel<<<M, 256, 0, stream>>>(fx32, ln1_w + i * CC, ln1_b + i * CC, xln);
    conv_mfma_kernel<<<BB * HH * 2, 256, 0, stream>>>(
        xln, wtfx + (size_t)i * 9 * CC * INNERC, convfx_b + i * INNERC, fxmid);
    conv_mfma_kernel<<<BB * HH * 2, 256, 0, stream>>>(
        xln, wtx + (size_t)i * 9 * CC * INNERC, convx_b + i * INNERC, xmid);
    slice_softmax_kernel<<<M / SSP, 256, 0, stream>>>(
        xmid, slice_w + i * DHD * GG, slice_b + i * GG, temperature + i * NHEADS, swb);
    slice_st_kernel<<<dim3(SPLIT, NHEADS, BB), 256, 0, stream>>>(fxmid, swb, stp, normp);
    attn_kernel<<<BB * NHEADS, 256, 0, stream>>>(
        stp, normp, wq + i * DHD * DHD, wk + i * DHD * DHD, wv + i * DHD * DHD, otb);
    wc_kernel<<<BB * NHEADS, 256, 0, stream>>>(otb, wo + (size_t)i * INNERC * CC, wct);
    // fx[b] += sw[b] @ Wc[b] + bo   (deslice + wo-projection fused)
    gemm_acc_kernel<<<dim3(NN / 128, CC / 128, BB), 256, 0, stream>>>(
        swb, wct, bo + i * CC, fx32, NN, CC, NHEADS * GG,
        (size_t)NN * (NHEADS * GG), (size_t)CC * (NHEADS * GG), (size_t)NN * CC);
    ln_kernel<<<M, 256, 0, stream>>>(fx32, ln2_w + i * CC, ln2_b + i * CC, xln);
    mlp_fused_kernel<<<M / 128, 512, 0, stream>>>(
        xln, w1t + (size_t)i * CC * HIDD, b1 + i * HIDD,
        w2t + (size_t)i * HIDD * CC, b2 + i * CC, fx32);
  }
  head_kernel<<<M, 256, 0, stream>>>(fx32, ln3_w, ln3_b, w_out, b_out, out);
}